// Round 6
// baseline (377.033 us; speedup 1.0000x reference)
//
#include <hip/hip_runtime.h>
#include <hip/hip_bf16.h>
#include <math.h>

// Problem constants (fixed shapes)
#define BATCH   2
#define TSEQ    2048
#define DEMBED  1024
#define NHEAD   16
#define DHEAD   64
#define NGROUP  4
#define ROPEN   32
#define FQKV    1536          // (16 + 2*4) * 64
#define MROWS   (BATCH*TSEQ)  // 4096

typedef __attribute__((ext_vector_type(8))) short short8;   // 8 bf16 = 4 VGPR
typedef __attribute__((ext_vector_type(4))) float floatx4;  // MFMA C/D

// ---------------------------------------------------------------------------
// split helpers: f = hi + lo, hi = truncate-to-bf16(f), lo = bf16(f - hi).
// ---------------------------------------------------------------------------
__device__ __forceinline__ void split_pack8(const float* f, uint4& h4, uint4& l4) {
    uint u[8], lu[8];
    #pragma unroll
    for (int j = 0; j < 8; ++j) {
        u[j] = __float_as_uint(f[j]);
        float lf = f[j] - __uint_as_float(u[j] & 0xffff0000u);
        lu[j] = __float_as_uint(lf);
    }
    h4.x = __builtin_amdgcn_perm(u[1], u[0], 0x07060302u);
    h4.y = __builtin_amdgcn_perm(u[3], u[2], 0x07060302u);
    h4.z = __builtin_amdgcn_perm(u[5], u[4], 0x07060302u);
    h4.w = __builtin_amdgcn_perm(u[7], u[6], 0x07060302u);
    l4.x = __builtin_amdgcn_perm(lu[1], lu[0], 0x07060302u);
    l4.y = __builtin_amdgcn_perm(lu[3], lu[2], 0x07060302u);
    l4.z = __builtin_amdgcn_perm(lu[5], lu[4], 0x07060302u);
    l4.w = __builtin_amdgcn_perm(lu[7], lu[6], 0x07060302u);
}

// round-to-nearest bf16 pack of 8 floats -> hi-only uint4 (unbiased)
__device__ __forceinline__ void rtn_pack8(const float* f, uint4& h4) {
    uint t[8];
    #pragma unroll
    for (int j = 0; j < 8; ++j)
        t[j] = __float_as_uint(f[j]) + 0x8000u;
    h4.x = __builtin_amdgcn_perm(t[1], t[0], 0x07060302u);
    h4.y = __builtin_amdgcn_perm(t[3], t[2], 0x07060302u);
    h4.z = __builtin_amdgcn_perm(t[5], t[4], 0x07060302u);
    h4.w = __builtin_amdgcn_perm(t[7], t[6], 0x07060302u);
}

// pack two floats -> one u32 of two RTN bf16 (lo = f0, hi = f1)
__device__ __forceinline__ uint pk_bf16x2(float f0, float f1) {
    uint u0 = __float_as_uint(f0) + 0x8000u;
    uint u1 = __float_as_uint(f1) + 0x8000u;
    return __builtin_amdgcn_perm(u1, u0, 0x07060302u);
}

// native 2^x (single VOP1; log2 scaling folded into operands upstream)
__device__ __forceinline__ float fast_exp2(float x) {
    float r;
    asm("v_exp_f32 %0, %1" : "=v"(r) : "v"(x));
    return r;
}

// async 16B/lane global->LDS copy; lds must be wave-uniform (HW adds lane*16)
__device__ __forceinline__ void lds_async16(void* lds, const void* gp) {
    __builtin_amdgcn_global_load_lds(
        (const __attribute__((address_space(1))) unsigned int*)gp,
        (__attribute__((address_space(3))) unsigned int*)lds,
        16, 0, 0);
}

// ===========================================================================
// MFMA-GEMM: pre-swizzled hi/lo bf16 images.
// Image layout (A and B^T): per (tile128, kblock64):
//   [hi: 128 rows x 128B][lo: 128 rows x 128B] = 32 KB, tile index = rt*16 + c.
//   Row r holds 64 bf16 k-values as 8 chunks of 16B; chunk j at phys j^(r&7).
// ===========================================================================

// ---- x converter: [4096][1024] f32 row-major -> A-image ----
__global__ __launch_bounds__(256) void conv_xy(const float* __restrict__ in,
                                               char* __restrict__ img) {
    const int tid = threadIdx.x;
    const int c   = blockIdx.x & 15;
    const int mt  = blockIdx.x >> 4;
    const int r    = tid >> 1;
    const int half = tid & 1;

    const float* src = in + (size_t)(mt*128 + r)*1024 + c*64 + half*32;
    float f[32];
    #pragma unroll
    for (int u = 0; u < 8; ++u)
        *(float4*)(f + 4*u) = *(const float4*)(src + 4*u);

    char* tile = img + ((size_t)(mt*16 + c)) * 32768;
    #pragma unroll
    for (int cc = 0; cc < 4; ++cc) {
        uint4 h4, l4;
        split_pack8(f + cc*8, h4, l4);
        int j    = half*4 + cc;
        int phys = j ^ (r & 7);
        *(uint4*)(tile + r*128 + phys*16)         = h4;
        *(uint4*)(tile + 16384 + r*128 + phys*16) = l4;
    }
}

// ---- weight converter (transpose): W [1024][N] f32 -> B^T image ----
__global__ __launch_bounds__(256) void conv_w(const float* __restrict__ W,
                                              int N,
                                              char* __restrict__ img) {
    __shared__ float Lf[64][132];
    const int tid = threadIdx.x;
    const int c   = blockIdx.x;
    const int nt  = blockIdx.y;

    {
        const int kk = tid >> 2;
        const int nc = (tid & 3) * 32;
        const float* src = W + (size_t)(c*64 + kk)*N + nt*128 + nc;
        #pragma unroll
        for (int u = 0; u < 8; ++u)
            *(float4*)(&Lf[kk][nc + 4*u]) = *(const float4*)(src + 4*u);
    }
    __syncthreads();

    char* tile = img + ((size_t)(nt*16 + c)) * 32768;
    #pragma unroll
    for (int rep = 0; rep < 4; ++rep) {
        int idx = rep*256 + tid;
        int n = idx & 127;
        int j = idx >> 7;
        float v[8];
        #pragma unroll
        for (int i = 0; i < 8; ++i) v[i] = Lf[j*8 + i][n];
        uint4 h4, l4;
        split_pack8(v, h4, l4);
        int phys = j ^ (n & 7);
        *(uint4*)(tile + n*128 + phys*16)         = h4;
        *(uint4*)(tile + 16384 + n*128 + phys*16) = l4;
    }
}

// ---- split-bf16 MFMA GEMM core: 128x128 tile, BK=64, 4 waves (2x2) ----
struct GemmAcc { floatx4 a[4][4]; };

__device__ __forceinline__ void gemm_mfma_core(const char* __restrict__ Aimg,
                                               const char* __restrict__ Bimg,
                                               char* smem, int mt, int nt,
                                               int tid, GemmAcc& G) {
    const int wv = tid >> 6;
    const int wm = wv & 1, wn = wv >> 1;
    const int lane = tid & 63;
    const int qd = lane >> 4, cl = lane & 15;
    const int wslot = (tid & 192) * 16;     // wave-uniform LDS byte offset

    #pragma unroll
    for (int tm = 0; tm < 4; ++tm)
        #pragma unroll
        for (int tn = 0; tn < 4; ++tn)
            G.a[tm][tn] = (floatx4){0.f, 0.f, 0.f, 0.f};

    for (int c = 0; c < 16; ++c) {
        __syncthreads();                    // prev-iter LDS reads complete
        {
            const uint4* gA = (const uint4*)(Aimg + ((size_t)(mt*16 + c)) * 32768) + tid;
            const uint4* gB = (const uint4*)(Bimg + ((size_t)(nt*16 + c)) * 32768) + tid;
            #pragma unroll
            for (int j = 0; j < 8; ++j) {
                lds_async16(smem + j*4096 + wslot,         gA + j*256);
                lds_async16(smem + 32768 + j*4096 + wslot, gB + j*256);
            }
        }
        __syncthreads();                    // vmcnt(0) drain publishes tile

        #pragma unroll
        for (int s = 0; s < 2; ++s) {
            const int phys = ((s*4 + qd) ^ (cl & 7)) * 16;
            short8 ah[4], al[4], bh[4], bl[4];
            #pragma unroll
            for (int tt = 0; tt < 4; ++tt) {
                const int rA = wm*64 + 16*tt + cl;
                ah[tt] = *(const short8*)(smem + rA*128 + phys);
                al[tt] = *(const short8*)(smem + 16384 + rA*128 + phys);
                const int rB = wn*64 + 16*tt + cl;
                bh[tt] = *(const short8*)(smem + 32768 + rB*128 + phys);
                bl[tt] = *(const short8*)(smem + 49152 + rB*128 + phys);
            }
            #pragma unroll
            for (int tm = 0; tm < 4; ++tm)
                #pragma unroll
                for (int tn = 0; tn < 4; ++tn) {
                    G.a[tm][tn] = __builtin_amdgcn_mfma_f32_16x16x32_bf16(ah[tm], bh[tn], G.a[tm][tn], 0, 0, 0);
                    G.a[tm][tn] = __builtin_amdgcn_mfma_f32_16x16x32_bf16(al[tm], bh[tn], G.a[tm][tn], 0, 0, 0);
                    G.a[tm][tn] = __builtin_amdgcn_mfma_f32_16x16x32_bf16(ah[tm], bl[tn], G.a[tm][tn], 0, 0, 0);
                }
        }
    }
}

// ---- qkv projection with fused RoPE + K/V image epilogue ----
// V image chunk contents are permuted to match attn's in-register P layout:
// chunk j (=4*hh+qd) of a 64-key tile holds keys {32hh+4qd..+3} then
// {32hh+16+4qd..+3} (was {8j..8j+7}).  attn-side addresses unchanged.
__global__ __launch_bounds__(256, 2) void gemm_qkv_mfma(const char* __restrict__ Aimg,
                                                        const char* __restrict__ Bimg,
                                                        const float* __restrict__ cosp,
                                                        const float* __restrict__ sinp,
                                                        float* __restrict__ Qf,
                                                        ushort* __restrict__ Kimg,
                                                        ushort* __restrict__ Vimg) {
    __shared__ __align__(16) char smem[68608];   // main loop uses [0,65536)
    const int tid = threadIdx.x;
    const int nt = blockIdx.x, mt = blockIdx.y;

    GemmAcc G;
    gemm_mfma_core(Aimg, Bimg, smem, mt, nt, tid, G);

    const int wv = tid >> 6;
    const int wm = wv & 1, wn = wv >> 1;
    const int lane = tid & 63;
    const int qd = lane >> 4, cl = lane & 15;

    const int slice = nt*2 + wn;          // 0..23
    const int g  = slice / 6;
    const int jj = slice % 6;
    const int b  = mt >> 4;

    // ---- RoPE in C-fragment space (Q and K): dims cl (tn=0) & 16+cl (tn=1)
    if (jj != 5) {
        #pragma unroll
        for (int tm = 0; tm < 4; ++tm)
            #pragma unroll
            for (int r = 0; r < 4; ++r) {
                int m = mt*128 + wm*64 + 16*tm + 4*qd + r;
                int t = m & 2047;
                float c1 = cosp[t*ROPEN + cl],      s1 = sinp[t*ROPEN + cl];
                float c2 = cosp[t*ROPEN + 16 + cl], s2 = sinp[t*ROPEN + 16 + cl];
                float x1 = G.a[tm][0][r], x2 = G.a[tm][1][r];
                G.a[tm][0][r] = x1*c1 - x2*s1;
                G.a[tm][1][r] = x2*c2 + x1*s2;
            }
    }

    if (jj < 4) {
        #pragma unroll
        for (int tm = 0; tm < 4; ++tm)
            #pragma unroll
            for (int tn = 0; tn < 4; ++tn)
                #pragma unroll
                for (int r = 0; r < 4; ++r) {
                    int m = mt*128 + wm*64 + 16*tm + 4*qd + r;
                    Qf[(size_t)m*1024 + (g*4 + jj)*64 + 16*tn + cl] = G.a[tm][tn][r];
                }
    } else {
        // K/V: wave-private LDS transpose -> swizzled image
        // K: exact hi/lo split (truncate).  V: RTN hi only (attn uses hi only).
        float* Lw = (float*)(smem + wv*17152);   // 64 x 67 f32
        __syncthreads();   // main-loop LDS reads complete (uniform: KV block)
        #pragma unroll
        for (int tm = 0; tm < 4; ++tm)
            #pragma unroll
            for (int tn = 0; tn < 4; ++tn)
                #pragma unroll
                for (int r = 0; r < 4; ++r)
                    Lw[(16*tm + 4*qd + r)*67 + 16*tn + cl] = G.a[tm][tn][r];
        __syncthreads();

        const int cloc = (mt & 15)*2 + wm;       // 64-key tile index within b
        ushort* img = ((jj == 4) ? Kimg : Vimg)
                      + (size_t)(b*4 + g)*262144 + (size_t)cloc*8192;
        if (jj == 4) {
            const int rr = lane;
            float f[8];
            #pragma unroll
            for (int ch = 0; ch < 8; ++ch) {
                *(float4*)f       = *(const float4*)(&Lw[rr*67 + ch*8]);
                *(float4*)(f + 4) = *(const float4*)(&Lw[rr*67 + ch*8 + 4]);
                uint4 h4, l4;
                split_pack8(f, h4, l4);
                int phys = ch ^ (rr & 7);
                *(uint4*)(img + rr*64 + phys*8)        = h4;
                *(uint4*)(img + 4096 + rr*64 + phys*8) = l4;
            }
        } else {
            // V: permuted-key chunk layout (see header comment)
            const int d = lane;
            float f[8];
            #pragma unroll
            for (int ch = 0; ch < 8; ++ch) {
                const int kb = 32*(ch >> 2) + 4*(ch & 3);
                #pragma unroll
                for (int i = 0; i < 4; ++i) f[i]     = Lw[(kb + i)*67 + d];
                #pragma unroll
                for (int i = 0; i < 4; ++i) f[4 + i] = Lw[(kb + 16 + i)*67 + d];
                uint4 h4;
                rtn_pack8(f, h4);
                int phys = ch ^ (d & 7);
                *(uint4*)(img + d*64 + phys*8) = h4;   // hi only
            }
        }
    }
}

// ---- output projection: out = yb @ Wout, 64M x 128N tiles ----
__global__ __launch_bounds__(256, 2) void gemm_out_mfma(const char* __restrict__ Aimg,
                                                        const char* __restrict__ Bimg,
                                                        float* __restrict__ C) {
    __shared__ __align__(16) char smem[49152];
    const int tid = threadIdx.x;
    const int nt = blockIdx.x, mt = blockIdx.y;   // mt: 64-row tile (0..63)

    const int wv = tid >> 6;
    const int wm = wv & 1, wn = wv >> 1;
    const int lane = tid & 63;
    const int qd = lane >> 4, cl = lane & 15;
    const int wslot = (tid & 192) * 16;

    floatx4 acc[2][4];
    #pragma unroll
    for (int tm = 0; tm < 2; ++tm)
        #pragma unroll
        for (int tn = 0; tn < 4; ++tn)
            acc[tm][tn] = (floatx4){0.f, 0.f, 0.f, 0.f};

    for (int c = 0; c < 16; ++c) {
        __syncthreads();
        {
            const char* sA = Aimg + ((size_t)((mt >> 1)*16 + c))*32768
                                  + (mt & 1)*8192 + (size_t)tid*16;
            const char* sB = Bimg + ((size_t)(nt*16 + c))*32768 + (size_t)tid*16;
            lds_async16(smem + wslot,          sA);
            lds_async16(smem + 4096  + wslot,  sA + 4096);
            lds_async16(smem + 8192  + wslot,  sA + 16384);
            lds_async16(smem + 12288 + wslot,  sA + 16384 + 4096);
            #pragma unroll
            for (int j = 0; j < 4; ++j) {
                lds_async16(smem + 16384 + j*4096 + wslot, sB + j*4096);
                lds_async16(smem + 32768 + j*4096 + wslot, sB + 16384 + j*4096);
            }
        }
        __syncthreads();

        #pragma unroll
        for (int s = 0; s < 2; ++s) {
            const int phys = ((s*4 + qd) ^ (cl & 7)) * 16;
            short8 ah[2], al[2], bh[4], bl[4];
            #pragma unroll
            for (int tt = 0; tt < 2; ++tt) {
                const int rA = wm*32 + 16*tt + cl;
                ah[tt] = *(const short8*)(smem + rA*128 + phys);
                al[tt] = *(const short8*)(smem + 8192 + rA*128 + phys);
            }
            #pragma unroll
            for (int tt = 0; tt < 4; ++tt) {
                const int rB = wn*64 + 16*tt + cl;
                bh[tt] = *(const short8*)(smem + 16384 + rB*128 + phys);
                bl[tt] = *(const short8*)(smem + 32768 + rB*128 + phys);
            }
            #pragma unroll
            for (int tm = 0; tm < 2; ++tm)
                #pragma unroll
                for (int tn = 0; tn < 4; ++tn) {
                    acc[tm][tn] = __builtin_amdgcn_mfma_f32_16x16x32_bf16(ah[tm], bh[tn], acc[tm][tn], 0, 0, 0);
                    acc[tm][tn] = __builtin_amdgcn_mfma_f32_16x16x32_bf16(al[tm], bh[tn], acc[tm][tn], 0, 0, 0);
                    acc[tm][tn] = __builtin_amdgcn_mfma_f32_16x16x32_bf16(ah[tm], bl[tn], acc[tm][tn], 0, 0, 0);
                }
        }
    }

    #pragma unroll
    for (int tm = 0; tm < 2; ++tm)
        #pragma unroll
        for (int tn = 0; tn < 4; ++tn)
            #pragma unroll
            for (int r = 0; r < 4; ++r) {
                int m = mt*64 + wm*32 + 16*tm + 4*qd + r;
                int n = nt*128 + wn*64 + 16*tn + cl;
                C[(size_t)m*1024 + n] = acc[tm][tn][r];
            }
}

// ---------------------------------------------------------------------------
// MFMA flash attention v12.  attn11 counters showed MfmaUtil=VALUBusy=34%,
// occupancy 33% (4 waves/SIMD), conflicts gone, HBM idle -> latency-chain
// bound with too few independent wave streams.  Fix: 512-thread blocks,
// 8 waves = (grp, wq); the 4 wq waves own 16 q-rows each, and the 2 grp
// groups split each staged 64-key K tile into its 32-key halves (grp
// replaces attn11's inner hh loop).  1024 blocks x 8 waves / 1024 SIMDs
// = 8 waves/SIMD = FULL occupancy (VGPR 52 <= 64, LDS 34.8K x 4 <= 160K).
// V loads issued BEFORE the K prefetch so PV's wait is vmcnt(2), leaving
// the prefetch in flight across the barrier.  End: grp=1 waves write
// (O^T, lsum) partials to LDS; grp=0 combines, normalizes, fills Lt; all
// 512 threads write the y A-image (one 16B chunk pair each).
// ---------------------------------------------------------------------------
__global__ __launch_bounds__(512, 8) void attn12(const float* __restrict__ Qf,
                                                 const char* __restrict__ Kimg,
                                                 const char* __restrict__ Vimg,
                                                 char* __restrict__ Yimg) {
    __shared__ __align__(16) char smem[34816];   // K dbuf 32K; epilogue reuse

    const int tid  = threadIdx.x;
    const int wv8  = tid >> 6;           // 0..7
    const int grp  = wv8 >> 2;           // key half within 64-key tile
    const int wq   = wv8 & 3;            // q quarter (16 rows)
    const int lane = tid & 63;
    const int qd   = lane >> 4;
    const int cl   = lane & 15;

    const int bg    = blockIdx.x & 7;    // XCD-aligned
    const int inner = blockIdx.x >> 3;
    const int hj    = inner >> 5;        // head within group (0..3)
    const int qt    = inner & 31;        // 64-row q tile (0..31)
    const int b = bg >> 2, g = bg & 3;
    const int h = g*4 + hj;

    // ---- Q fragments (rows 16*wq..+15) -> registers, scaled log2(e)/8 ----
    short8 qh[2], ql[2];
    {
        const float* qp = Qf + (size_t)(b*2048 + qt*64 + wq*16 + cl)*1024
                             + h*64 + 8*qd;
        #pragma unroll
        for (int s = 0; s < 2; ++s) {
            float f[8];
            *(float4*)f       = *(const float4*)(qp + 32*s);
            *(float4*)(f + 4) = *(const float4*)(qp + 32*s + 4);
            #pragma unroll
            for (int i = 0; i < 8; ++i) f[i] *= 0.125f * 1.44269504088896f;
            uint4 h4, l4;
            split_pack8(f, h4, l4);
            qh[s] = __builtin_bit_cast(short8, h4);
            ql[s] = __builtin_bit_cast(short8, l4);
        }
    }

    floatx4 accOT[4] = {};               // O^T partial: [d-block], q = cl
    float lsum = 0.f;                    // softmax denom partial

    const char* Kg0 = Kimg + (size_t)bg*524288;
    const char* Vg0 = Vimg + (size_t)bg*524288;
    const int wslot = wv8 << 10;         // wave-uniform LDS byte offset (1K)

    // lane-constant V offsets (chunk 4*grp+qd, phys ^(cl&7))
    int voff[4];
    #pragma unroll
    for (int tt = 0; tt < 4; ++tt)
        voff[tt] = (16*tt + cl)*128 + (((4*grp + qd) ^ (cl & 7))*16);

    // stage K 64-key tile 0 into buf 0 (hi 8K + lo 8K, image-linear):
    // 8 waves x 2 async 1K chunks
    {
        const char* src = Kg0 + (size_t)tid*16;
        lds_async16(smem + wslot,        src);
        lds_async16(smem + 8192 + wslot, src + 8192);
    }

    for (int c = 0; c < TSEQ/64; ++c) {
        __syncthreads();   // publishes K tile c; all reads of c-1 complete
        const int buf = c & 1;
        const char* Vg = Vg0 + (size_t)c*16384;

        // ---- V loads first: consumed by PV with vmcnt(2) -> the K
        //      prefetch issued below stays in flight across the barrier ----
        short8 vh[4];
        #pragma unroll
        for (int tt = 0; tt < 4; ++tt)
            vh[tt] = *(const short8*)(Vg + voff[tt]);

        if (c + 1 < TSEQ/64) {
            const char* src = Kg0 + (size_t)(c+1)*16384 + (size_t)tid*16;
            lds_async16(smem + (1-buf)*16384 + wslot,        src);
            lds_async16(smem + (1-buf)*16384 + 8192 + wslot, src + 8192);
        }
        const char* Kl = smem + buf*16384;

        // ---- S^T = K.Q^T for this wave's 32-key half (3-pass split) ----
        floatx4 accST[2] = {};
        __builtin_amdgcn_s_setprio(1);
        #pragma unroll
        for (int s = 0; s < 2; ++s) {
            #pragma unroll
            for (int tt = 0; tt < 2; ++tt) {
                const int off = (32*grp + 16*tt + cl)*128
                              + (((4*s + qd) ^ (cl & 7))*16);
                short8 kh = *(const short8*)(Kl + off);
                short8 kl = *(const short8*)(Kl + 8192 + off);
                accST[tt] = __builtin_amdgcn_mfma_f32_16x16x32_bf16(kh, qh[s], accST[tt], 0, 0, 0);
                accST[tt] = __builtin_amdgcn_mfma_f32_16x16x32_bf16(kh, ql[s], accST[tt], 0, 0, 0);
                accST[tt] = __builtin_amdgcn_mfma_f32_16x16x32_bf16(kl, qh[s], accST[tt], 0, 0, 0);
            }
        }
        __builtin_amdgcn_s_setprio(0);

        // ---- softmax: exp2 (S in log2 units), pack in-register ----
        float p[8];
        #pragma unroll
        for (int tt = 0; tt < 2; ++tt)
            #pragma unroll
            for (int r = 0; r < 4; ++r)
                p[4*tt + r] = fast_exp2(accST[tt][r]);
        lsum += ((p[0] + p[1]) + (p[2] + p[3]))
              + ((p[4] + p[5]) + (p[6] + p[7]));
        uint4 paw;
        paw.x = pk_bf16x2(p[0], p[1]);
        paw.y = pk_bf16x2(p[2], p[3]);
        paw.z = pk_bf16x2(p[4], p[5]);
        paw.w = pk_bf16x2(p[6], p[7]);
        short8 pa = __builtin_bit_cast(short8, paw);

        // ---- O^T += V.P (V chunks pre-permuted to the same key order) ----
        __builtin_amdgcn_s_setprio(1);
        #pragma unroll
        for (int tt = 0; tt < 4; ++tt)
            accOT[tt] = __builtin_amdgcn_mfma_f32_16x16x32_bf16(vh[tt], pa, accOT[tt], 0, 0, 0);
        __builtin_amdgcn_s_setprio(0);
    }

    // ---- combine the two key-half groups, normalize, write y A-image ----
    __syncthreads();                 // all waves done with K buffers
    float* Pb = (float*)smem;        // grp=1 partials: 256 lanes x 17 f32
    if (grp == 1) {
        float* dst = Pb + (size_t)(wq*64 + lane)*17;
        #pragma unroll
        for (int tt = 0; tt < 4; ++tt)
            #pragma unroll
            for (int r = 0; r < 4; ++r)
                dst[4*tt + r] = accOT[tt][r];
        dst[16] = lsum;
    }
    __syncthreads();
    float* Lt = (float*)(smem + 17920);  // 64 rows x 66 f32 = 16896 B
    if (grp == 0) {
        const float* sp = Pb + (size_t)(wq*64 + lane)*17;
        #pragma unroll
        for (int tt = 0; tt < 4; ++tt)
            #pragma unroll
            for (int r = 0; r < 4; ++r)
                accOT[tt][r] += sp[4*tt + r];
        float l = lsum + sp[16];
        l += __shfl_xor(l, 16);
        l += __shfl_xor(l, 32);
        float inv = 1.0f / l;
        const int row = 16*wq + cl;  // q row
        #pragma unroll
        for (int tt = 0; tt < 4; ++tt)
            #pragma unroll
            for (int r = 0; r < 4; ++r)
                Lt[row*66 + 16*tt + 4*qd + r] = accOT[tt][r] * inv;
    }
    __syncthreads();
    {
        const int r0 = tid >> 3;     // 0..63 (q row)
        const int qq = tid & 7;      // 8-col chunk
        float f[8];
        #pragma unroll
        for (int u = 0; u < 4; ++u)
            *(float2*)(f + 2*u) = *(const float2*)(&Lt[r0*66 + qq*8 + 2*u]);
        const int R = (qt & 1)*64 + r0;              // row within 128-row Y tile
        char* tile = Yimg + (size_t)((b*16 + (qt >> 1))*16 + h) * 32768;
        uint4 h4, l4;
        split_pack8(f, h4, l4);
        int phys = qq ^ (R & 7);
        *(uint4*)(tile + R*128 + phys*16)         = h4;
        *(uint4*)(tile + 16384 + R*128 + phys*16) = l4;
    }
}

// ---------------------------------------------------------------------------
extern "C" void kernel_launch(void* const* d_in, const int* in_sizes, int n_in,
                              void* d_out, int out_size, void* d_ws, size_t ws_size,
                              hipStream_t stream) {
    const float* x    = (const float*)d_in[0];
    const float* cosp = (const float*)d_in[1];
    const float* sinp = (const float*)d_in[2];
    // d_in[3] = mask: unused by the reference computation
    const float* Wqkv = (const float*)d_in[4];
    const float* Wout = (const float*)d_in[5];
    float* out = (float*)d_out;

    char* ws = (char*)d_ws;
    float*  Qf    = (float*)(ws);                      // [ 0,16M)
    ushort* Kimg  = (ushort*)(ws + ((size_t)16<<20));  // [16,20M)
    ushort* Vimg  = (ushort*)(ws + ((size_t)20<<20));  // [20,24M)
    char*   Bo    = ws + ((size_t)24<<20);             // [24,28M)
    char*   Ximg  = ws + ((size_t)28<<20);             // [28,44M)  (dead after qkv-gemm)
    char*   Bq    = ws + ((size_t)44<<20);             // [44,50M)
    char*   Yimg  = ws + ((size_t)28<<20);             // [28,44M)  (over dead Ximg)

    // 1) input + weight images
    conv_xy<<<512, 256, 0, stream>>>(x, Ximg);
    conv_w<<<dim3(16, 12), 256, 0, stream>>>(Wqkv, FQKV, Bq);
    conv_w<<<dim3(16, 8), 256, 0, stream>>>(Wout, DEMBED, Bo);
    // 2) qkv projection + fused RoPE + K/V image build
    gemm_qkv_mfma<<<dim3(12, 32), 256, 0, stream>>>(Ximg, Bq, cosp, sinp,
                                                    Qf, Kimg, Vimg);
    // 3) attention (1024 blocks x 512 thr = 8 waves/SIMD, full occupancy)
    attn12<<<1024, 512, 0, stream>>>(Qf, (const char*)Kimg, (const char*)Vimg,
                                     Yimg);
    // 4) out = y @ Wout
    gemm_out_mfma<<<dim3(8, 64), 256, 0, stream>>>(Yimg, Bo, out);
}

// Round 7
// 244.390 us; speedup vs baseline: 1.5428x; 1.5428x over previous
//
#include <hip/hip_runtime.h>
#include <hip/hip_bf16.h>
#include <math.h>

// Problem constants (fixed shapes)
#define BATCH   2
#define TSEQ    2048
#define DEMBED  1024
#define NHEAD   16
#define DHEAD   64
#define NGROUP  4
#define ROPEN   32
#define FQKV    1536          // (16 + 2*4) * 64
#define MROWS   (BATCH*TSEQ)  // 4096

typedef __attribute__((ext_vector_type(8))) short short8;   // 8 bf16 = 4 VGPR
typedef __attribute__((ext_vector_type(4))) float floatx4;  // MFMA C/D

// ---------------------------------------------------------------------------
// split helpers: f = hi + lo, hi = truncate-to-bf16(f), lo = bf16(f - hi).
// ---------------------------------------------------------------------------
__device__ __forceinline__ void split_pack8(const float* f, uint4& h4, uint4& l4) {
    uint u[8], lu[8];
    #pragma unroll
    for (int j = 0; j < 8; ++j) {
        u[j] = __float_as_uint(f[j]);
        float lf = f[j] - __uint_as_float(u[j] & 0xffff0000u);
        lu[j] = __float_as_uint(lf);
    }
    h4.x = __builtin_amdgcn_perm(u[1], u[0], 0x07060302u);
    h4.y = __builtin_amdgcn_perm(u[3], u[2], 0x07060302u);
    h4.z = __builtin_amdgcn_perm(u[5], u[4], 0x07060302u);
    h4.w = __builtin_amdgcn_perm(u[7], u[6], 0x07060302u);
    l4.x = __builtin_amdgcn_perm(lu[1], lu[0], 0x07060302u);
    l4.y = __builtin_amdgcn_perm(lu[3], lu[2], 0x07060302u);
    l4.z = __builtin_amdgcn_perm(lu[5], lu[4], 0x07060302u);
    l4.w = __builtin_amdgcn_perm(lu[7], lu[6], 0x07060302u);
}

// round-to-nearest bf16 pack of 8 floats -> hi-only uint4 (unbiased)
__device__ __forceinline__ void rtn_pack8(const float* f, uint4& h4) {
    uint t[8];
    #pragma unroll
    for (int j = 0; j < 8; ++j)
        t[j] = __float_as_uint(f[j]) + 0x8000u;
    h4.x = __builtin_amdgcn_perm(t[1], t[0], 0x07060302u);
    h4.y = __builtin_amdgcn_perm(t[3], t[2], 0x07060302u);
    h4.z = __builtin_amdgcn_perm(t[5], t[4], 0x07060302u);
    h4.w = __builtin_amdgcn_perm(t[7], t[6], 0x07060302u);
}

// pack two floats -> one u32 of two RTN bf16 (lo = f0, hi = f1)
__device__ __forceinline__ uint pk_bf16x2(float f0, float f1) {
    uint u0 = __float_as_uint(f0) + 0x8000u;
    uint u1 = __float_as_uint(f1) + 0x8000u;
    return __builtin_amdgcn_perm(u1, u0, 0x07060302u);
}

// native 2^x (single VOP1; log2 scaling folded into operands upstream)
__device__ __forceinline__ float fast_exp2(float x) {
    float r;
    asm("v_exp_f32 %0, %1" : "=v"(r) : "v"(x));
    return r;
}

// async 16B/lane global->LDS copy; lds must be wave-uniform (HW adds lane*16)
__device__ __forceinline__ void lds_async16(void* lds, const void* gp) {
    __builtin_amdgcn_global_load_lds(
        (const __attribute__((address_space(1))) unsigned int*)gp,
        (__attribute__((address_space(3))) unsigned int*)lds,
        16, 0, 0);
}

// ===========================================================================
// MFMA-GEMM: pre-swizzled hi/lo bf16 images.
// Image layout (A and B^T): per (tile128, kblock64):
//   [hi: 128 rows x 128B][lo: 128 rows x 128B] = 32 KB, tile index = rt*16 + c.
//   Row r holds 64 bf16 k-values as 8 chunks of 16B; chunk j at phys j^(r&7).
// ===========================================================================

// ---- x converter: [4096][1024] f32 row-major -> A-image ----
__global__ __launch_bounds__(256) void conv_xy(const float* __restrict__ in,
                                               char* __restrict__ img) {
    const int tid = threadIdx.x;
    const int c   = blockIdx.x & 15;
    const int mt  = blockIdx.x >> 4;
    const int r    = tid >> 1;
    const int half = tid & 1;

    const float* src = in + (size_t)(mt*128 + r)*1024 + c*64 + half*32;
    float f[32];
    #pragma unroll
    for (int u = 0; u < 8; ++u)
        *(float4*)(f + 4*u) = *(const float4*)(src + 4*u);

    char* tile = img + ((size_t)(mt*16 + c)) * 32768;
    #pragma unroll
    for (int cc = 0; cc < 4; ++cc) {
        uint4 h4, l4;
        split_pack8(f + cc*8, h4, l4);
        int j    = half*4 + cc;
        int phys = j ^ (r & 7);
        *(uint4*)(tile + r*128 + phys*16)         = h4;
        *(uint4*)(tile + 16384 + r*128 + phys*16) = l4;
    }
}

// ---- weight converter (transpose): W [1024][N] f32 -> B^T image ----
__global__ __launch_bounds__(256) void conv_w(const float* __restrict__ W,
                                              int N,
                                              char* __restrict__ img) {
    __shared__ float Lf[64][132];
    const int tid = threadIdx.x;
    const int c   = blockIdx.x;
    const int nt  = blockIdx.y;

    {
        const int kk = tid >> 2;
        const int nc = (tid & 3) * 32;
        const float* src = W + (size_t)(c*64 + kk)*N + nt*128 + nc;
        #pragma unroll
        for (int u = 0; u < 8; ++u)
            *(float4*)(&Lf[kk][nc + 4*u]) = *(const float4*)(src + 4*u);
    }
    __syncthreads();

    char* tile = img + ((size_t)(nt*16 + c)) * 32768;
    #pragma unroll
    for (int rep = 0; rep < 4; ++rep) {
        int idx = rep*256 + tid;
        int n = idx & 127;
        int j = idx >> 7;
        float v[8];
        #pragma unroll
        for (int i = 0; i < 8; ++i) v[i] = Lf[j*8 + i][n];
        uint4 h4, l4;
        split_pack8(v, h4, l4);
        int phys = j ^ (n & 7);
        *(uint4*)(tile + n*128 + phys*16)         = h4;
        *(uint4*)(tile + 16384 + n*128 + phys*16) = l4;
    }
}

// ---- split-bf16 MFMA GEMM core: 128x128 tile, BK=64, 4 waves (2x2) ----
struct GemmAcc { floatx4 a[4][4]; };

__device__ __forceinline__ void gemm_mfma_core(const char* __restrict__ Aimg,
                                               const char* __restrict__ Bimg,
                                               char* smem, int mt, int nt,
                                               int tid, GemmAcc& G) {
    const int wv = tid >> 6;
    const int wm = wv & 1, wn = wv >> 1;
    const int lane = tid & 63;
    const int qd = lane >> 4, cl = lane & 15;
    const int wslot = (tid & 192) * 16;     // wave-uniform LDS byte offset

    #pragma unroll
    for (int tm = 0; tm < 4; ++tm)
        #pragma unroll
        for (int tn = 0; tn < 4; ++tn)
            G.a[tm][tn] = (floatx4){0.f, 0.f, 0.f, 0.f};

    for (int c = 0; c < 16; ++c) {
        __syncthreads();                    // prev-iter LDS reads complete
        {
            const uint4* gA = (const uint4*)(Aimg + ((size_t)(mt*16 + c)) * 32768) + tid;
            const uint4* gB = (const uint4*)(Bimg + ((size_t)(nt*16 + c)) * 32768) + tid;
            #pragma unroll
            for (int j = 0; j < 8; ++j) {
                lds_async16(smem + j*4096 + wslot,         gA + j*256);
                lds_async16(smem + 32768 + j*4096 + wslot, gB + j*256);
            }
        }
        __syncthreads();                    // vmcnt(0) drain publishes tile

        #pragma unroll
        for (int s = 0; s < 2; ++s) {
            const int phys = ((s*4 + qd) ^ (cl & 7)) * 16;
            short8 ah[4], al[4], bh[4], bl[4];
            #pragma unroll
            for (int tt = 0; tt < 4; ++tt) {
                const int rA = wm*64 + 16*tt + cl;
                ah[tt] = *(const short8*)(smem + rA*128 + phys);
                al[tt] = *(const short8*)(smem + 16384 + rA*128 + phys);
                const int rB = wn*64 + 16*tt + cl;
                bh[tt] = *(const short8*)(smem + 32768 + rB*128 + phys);
                bl[tt] = *(const short8*)(smem + 49152 + rB*128 + phys);
            }
            #pragma unroll
            for (int tm = 0; tm < 4; ++tm)
                #pragma unroll
                for (int tn = 0; tn < 4; ++tn) {
                    G.a[tm][tn] = __builtin_amdgcn_mfma_f32_16x16x32_bf16(ah[tm], bh[tn], G.a[tm][tn], 0, 0, 0);
                    G.a[tm][tn] = __builtin_amdgcn_mfma_f32_16x16x32_bf16(al[tm], bh[tn], G.a[tm][tn], 0, 0, 0);
                    G.a[tm][tn] = __builtin_amdgcn_mfma_f32_16x16x32_bf16(ah[tm], bl[tn], G.a[tm][tn], 0, 0, 0);
                }
        }
    }
}

// ---- qkv projection with fused RoPE + K/V image epilogue ----
// V image chunk contents are permuted to match attn's in-register P layout:
// chunk j (=4*hh+qd) of a 64-key tile holds keys {32hh+4qd..+3} then
// {32hh+16+4qd..+3} (was {8j..8j+7}).  attn-side addresses unchanged.
__global__ __launch_bounds__(256, 2) void gemm_qkv_mfma(const char* __restrict__ Aimg,
                                                        const char* __restrict__ Bimg,
                                                        const float* __restrict__ cosp,
                                                        const float* __restrict__ sinp,
                                                        float* __restrict__ Qf,
                                                        ushort* __restrict__ Kimg,
                                                        ushort* __restrict__ Vimg) {
    __shared__ __align__(16) char smem[68608];   // main loop uses [0,65536)
    const int tid = threadIdx.x;
    const int nt = blockIdx.x, mt = blockIdx.y;

    GemmAcc G;
    gemm_mfma_core(Aimg, Bimg, smem, mt, nt, tid, G);

    const int wv = tid >> 6;
    const int wm = wv & 1, wn = wv >> 1;
    const int lane = tid & 63;
    const int qd = lane >> 4, cl = lane & 15;

    const int slice = nt*2 + wn;          // 0..23
    const int g  = slice / 6;
    const int jj = slice % 6;
    const int b  = mt >> 4;

    // ---- RoPE in C-fragment space (Q and K): dims cl (tn=0) & 16+cl (tn=1)
    if (jj != 5) {
        #pragma unroll
        for (int tm = 0; tm < 4; ++tm)
            #pragma unroll
            for (int r = 0; r < 4; ++r) {
                int m = mt*128 + wm*64 + 16*tm + 4*qd + r;
                int t = m & 2047;
                float c1 = cosp[t*ROPEN + cl],      s1 = sinp[t*ROPEN + cl];
                float c2 = cosp[t*ROPEN + 16 + cl], s2 = sinp[t*ROPEN + 16 + cl];
                float x1 = G.a[tm][0][r], x2 = G.a[tm][1][r];
                G.a[tm][0][r] = x1*c1 - x2*s1;
                G.a[tm][1][r] = x2*c2 + x1*s2;
            }
    }

    if (jj < 4) {
        #pragma unroll
        for (int tm = 0; tm < 4; ++tm)
            #pragma unroll
            for (int tn = 0; tn < 4; ++tn)
                #pragma unroll
                for (int r = 0; r < 4; ++r) {
                    int m = mt*128 + wm*64 + 16*tm + 4*qd + r;
                    Qf[(size_t)m*1024 + (g*4 + jj)*64 + 16*tn + cl] = G.a[tm][tn][r];
                }
    } else {
        // K/V: wave-private LDS transpose -> swizzled image
        // K: exact hi/lo split (truncate).  V: RTN hi only (attn uses hi only).
        float* Lw = (float*)(smem + wv*17152);   // 64 x 67 f32
        __syncthreads();   // main-loop LDS reads complete (uniform: KV block)
        #pragma unroll
        for (int tm = 0; tm < 4; ++tm)
            #pragma unroll
            for (int tn = 0; tn < 4; ++tn)
                #pragma unroll
                for (int r = 0; r < 4; ++r)
                    Lw[(16*tm + 4*qd + r)*67 + 16*tn + cl] = G.a[tm][tn][r];
        __syncthreads();

        const int cloc = (mt & 15)*2 + wm;       // 64-key tile index within b
        ushort* img = ((jj == 4) ? Kimg : Vimg)
                      + (size_t)(b*4 + g)*262144 + (size_t)cloc*8192;
        if (jj == 4) {
            const int rr = lane;
            float f[8];
            #pragma unroll
            for (int ch = 0; ch < 8; ++ch) {
                *(float4*)f       = *(const float4*)(&Lw[rr*67 + ch*8]);
                *(float4*)(f + 4) = *(const float4*)(&Lw[rr*67 + ch*8 + 4]);
                uint4 h4, l4;
                split_pack8(f, h4, l4);
                int phys = ch ^ (rr & 7);
                *(uint4*)(img + rr*64 + phys*8)        = h4;
                *(uint4*)(img + 4096 + rr*64 + phys*8) = l4;
            }
        } else {
            // V: permuted-key chunk layout (see header comment)
            const int d = lane;
            float f[8];
            #pragma unroll
            for (int ch = 0; ch < 8; ++ch) {
                const int kb = 32*(ch >> 2) + 4*(ch & 3);
                #pragma unroll
                for (int i = 0; i < 4; ++i) f[i]     = Lw[(kb + i)*67 + d];
                #pragma unroll
                for (int i = 0; i < 4; ++i) f[4 + i] = Lw[(kb + 16 + i)*67 + d];
                uint4 h4;
                rtn_pack8(f, h4);
                int phys = ch ^ (d & 7);
                *(uint4*)(img + d*64 + phys*8) = h4;   // hi only
            }
        }
    }
}

// ---- output projection: out = yb @ Wout, 64M x 128N tiles ----
__global__ __launch_bounds__(256, 2) void gemm_out_mfma(const char* __restrict__ Aimg,
                                                        const char* __restrict__ Bimg,
                                                        float* __restrict__ C) {
    __shared__ __align__(16) char smem[49152];
    const int tid = threadIdx.x;
    const int nt = blockIdx.x, mt = blockIdx.y;   // mt: 64-row tile (0..63)

    const int wv = tid >> 6;
    const int wm = wv & 1, wn = wv >> 1;
    const int lane = tid & 63;
    const int qd = lane >> 4, cl = lane & 15;
    const int wslot = (tid & 192) * 16;

    floatx4 acc[2][4];
    #pragma unroll
    for (int tm = 0; tm < 2; ++tm)
        #pragma unroll
        for (int tn = 0; tn < 4; ++tn)
            acc[tm][tn] = (floatx4){0.f, 0.f, 0.f, 0.f};

    for (int c = 0; c < 16; ++c) {
        __syncthreads();
        {
            const char* sA = Aimg + ((size_t)((mt >> 1)*16 + c))*32768
                                  + (mt & 1)*8192 + (size_t)tid*16;
            const char* sB = Bimg + ((size_t)(nt*16 + c))*32768 + (size_t)tid*16;
            lds_async16(smem + wslot,          sA);
            lds_async16(smem + 4096  + wslot,  sA + 4096);
            lds_async16(smem + 8192  + wslot,  sA + 16384);
            lds_async16(smem + 12288 + wslot,  sA + 16384 + 4096);
            #pragma unroll
            for (int j = 0; j < 4; ++j) {
                lds_async16(smem + 16384 + j*4096 + wslot, sB + j*4096);
                lds_async16(smem + 32768 + j*4096 + wslot, sB + 16384 + j*4096);
            }
        }
        __syncthreads();

        #pragma unroll
        for (int s = 0; s < 2; ++s) {
            const int phys = ((s*4 + qd) ^ (cl & 7)) * 16;
            short8 ah[2], al[2], bh[4], bl[4];
            #pragma unroll
            for (int tt = 0; tt < 2; ++tt) {
                const int rA = wm*32 + 16*tt + cl;
                ah[tt] = *(const short8*)(smem + rA*128 + phys);
                al[tt] = *(const short8*)(smem + 8192 + rA*128 + phys);
            }
            #pragma unroll
            for (int tt = 0; tt < 4; ++tt) {
                const int rB = wn*64 + 16*tt + cl;
                bh[tt] = *(const short8*)(smem + 16384 + rB*128 + phys);
                bl[tt] = *(const short8*)(smem + 32768 + rB*128 + phys);
            }
            #pragma unroll
            for (int tm = 0; tm < 2; ++tm)
                #pragma unroll
                for (int tn = 0; tn < 4; ++tn) {
                    acc[tm][tn] = __builtin_amdgcn_mfma_f32_16x16x32_bf16(ah[tm], bh[tn], acc[tm][tn], 0, 0, 0);
                    acc[tm][tn] = __builtin_amdgcn_mfma_f32_16x16x32_bf16(al[tm], bh[tn], acc[tm][tn], 0, 0, 0);
                    acc[tm][tn] = __builtin_amdgcn_mfma_f32_16x16x32_bf16(ah[tm], bl[tn], acc[tm][tn], 0, 0, 0);
                }
        }
    }

    #pragma unroll
    for (int tm = 0; tm < 2; ++tm)
        #pragma unroll
        for (int tn = 0; tn < 4; ++tn)
            #pragma unroll
            for (int r = 0; r < 4; ++r) {
                int m = mt*64 + wm*32 + 16*tm + 4*qd + r;
                int n = nt*128 + wn*64 + 16*tn + cl;
                C[(size_t)m*1024 + n] = acc[tm][tn][r];
            }
}

// ---------------------------------------------------------------------------
// MFMA flash attention v13 = v12 structure with the register-allocation fix.
// v12's __launch_bounds__(512, 8) made the allocator emit 32-VGPR code with
// massive scratch spills (FETCH 11 MB -> 176 MB, 2.7x slower).  v13 declares
// (512, 4): VGPR cap 128, natural allocation ~52-60 (v11 measured 52 for the
// same per-wave state).  Runtime occupancy is then resource-limited, not
// bound-limited: LDS 34.8K -> 4 blocks/CU; if VGPR <= 64 the HW runs all
// 32 waves/CU = 8 waves/SIMD (full).  Structure: 512-thread blocks, 8 waves
// = (grp, wq); wq waves own 16 q-rows, grp groups split each staged 64-key
// K tile into 32-key halves.  V loads issued before the K prefetch; P stays
// in registers (permuted V image); grp partials combined through LDS at end.
// ---------------------------------------------------------------------------
__global__ __launch_bounds__(512, 4) void attn13(const float* __restrict__ Qf,
                                                 const char* __restrict__ Kimg,
                                                 const char* __restrict__ Vimg,
                                                 char* __restrict__ Yimg) {
    __shared__ __align__(16) char smem[34816];   // K dbuf 32K; epilogue reuse

    const int tid  = threadIdx.x;
    const int wv8  = tid >> 6;           // 0..7
    const int grp  = wv8 >> 2;           // key half within 64-key tile
    const int wq   = wv8 & 3;            // q quarter (16 rows)
    const int lane = tid & 63;
    const int qd   = lane >> 4;
    const int cl   = lane & 15;

    const int bg    = blockIdx.x & 7;    // XCD-aligned
    const int inner = blockIdx.x >> 3;
    const int hj    = inner >> 5;        // head within group (0..3)
    const int qt    = inner & 31;        // 64-row q tile (0..31)
    const int b = bg >> 2, g = bg & 3;
    const int h = g*4 + hj;

    // ---- Q fragments (rows 16*wq..+15) -> registers, scaled log2(e)/8 ----
    short8 qh[2], ql[2];
    {
        const float* qp = Qf + (size_t)(b*2048 + qt*64 + wq*16 + cl)*1024
                             + h*64 + 8*qd;
        #pragma unroll
        for (int s = 0; s < 2; ++s) {
            float f[8];
            *(float4*)f       = *(const float4*)(qp + 32*s);
            *(float4*)(f + 4) = *(const float4*)(qp + 32*s + 4);
            #pragma unroll
            for (int i = 0; i < 8; ++i) f[i] *= 0.125f * 1.44269504088896f;
            uint4 h4, l4;
            split_pack8(f, h4, l4);
            qh[s] = __builtin_bit_cast(short8, h4);
            ql[s] = __builtin_bit_cast(short8, l4);
        }
    }

    floatx4 accOT[4] = {};               // O^T partial: [d-block], q = cl
    float lsum = 0.f;                    // softmax denom partial

    const char* Kg0 = Kimg + (size_t)bg*524288;
    const char* Vg0 = Vimg + (size_t)bg*524288;
    const int wslot = wv8 << 10;         // wave-uniform LDS byte offset (1K)

    // lane-constant V offsets (chunk 4*grp+qd, phys ^(cl&7))
    int voff[4];
    #pragma unroll
    for (int tt = 0; tt < 4; ++tt)
        voff[tt] = (16*tt + cl)*128 + (((4*grp + qd) ^ (cl & 7))*16);

    // stage K 64-key tile 0 into buf 0 (hi 8K + lo 8K, image-linear):
    // 8 waves x 2 async 1K chunks
    {
        const char* src = Kg0 + (size_t)tid*16;
        lds_async16(smem + wslot,        src);
        lds_async16(smem + 8192 + wslot, src + 8192);
    }

    for (int c = 0; c < TSEQ/64; ++c) {
        __syncthreads();   // publishes K tile c; all reads of c-1 complete
        const int buf = c & 1;
        const char* Vg = Vg0 + (size_t)c*16384;

        // ---- V loads first: consumed by PV with vmcnt(2) -> the K
        //      prefetch issued below stays in flight across the barrier ----
        short8 vh[4];
        #pragma unroll
        for (int tt = 0; tt < 4; ++tt)
            vh[tt] = *(const short8*)(Vg + voff[tt]);

        if (c + 1 < TSEQ/64) {
            const char* src = Kg0 + (size_t)(c+1)*16384 + (size_t)tid*16;
            lds_async16(smem + (1-buf)*16384 + wslot,        src);
            lds_async16(smem + (1-buf)*16384 + 8192 + wslot, src + 8192);
        }
        const char* Kl = smem + buf*16384;

        // ---- S^T = K.Q^T for this wave's 32-key half (3-pass split) ----
        floatx4 accST[2] = {};
        __builtin_amdgcn_s_setprio(1);
        #pragma unroll
        for (int s = 0; s < 2; ++s) {
            #pragma unroll
            for (int tt = 0; tt < 2; ++tt) {
                const int off = (32*grp + 16*tt + cl)*128
                              + (((4*s + qd) ^ (cl & 7))*16);
                short8 kh = *(const short8*)(Kl + off);
                short8 kl = *(const short8*)(Kl + 8192 + off);
                accST[tt] = __builtin_amdgcn_mfma_f32_16x16x32_bf16(kh, qh[s], accST[tt], 0, 0, 0);
                accST[tt] = __builtin_amdgcn_mfma_f32_16x16x32_bf16(kh, ql[s], accST[tt], 0, 0, 0);
                accST[tt] = __builtin_amdgcn_mfma_f32_16x16x32_bf16(kl, qh[s], accST[tt], 0, 0, 0);
            }
        }
        __builtin_amdgcn_s_setprio(0);

        // ---- softmax: exp2 (S in log2 units), pack in-register ----
        float p[8];
        #pragma unroll
        for (int tt = 0; tt < 2; ++tt)
            #pragma unroll
            for (int r = 0; r < 4; ++r)
                p[4*tt + r] = fast_exp2(accST[tt][r]);
        lsum += ((p[0] + p[1]) + (p[2] + p[3]))
              + ((p[4] + p[5]) + (p[6] + p[7]));
        uint4 paw;
        paw.x = pk_bf16x2(p[0], p[1]);
        paw.y = pk_bf16x2(p[2], p[3]);
        paw.z = pk_bf16x2(p[4], p[5]);
        paw.w = pk_bf16x2(p[6], p[7]);
        short8 pa = __builtin_bit_cast(short8, paw);

        // ---- O^T += V.P (V chunks pre-permuted to the same key order) ----
        __builtin_amdgcn_s_setprio(1);
        #pragma unroll
        for (int tt = 0; tt < 4; ++tt)
            accOT[tt] = __builtin_amdgcn_mfma_f32_16x16x32_bf16(vh[tt], pa, accOT[tt], 0, 0, 0);
        __builtin_amdgcn_s_setprio(0);
    }

    // ---- combine the two key-half groups, normalize, write y A-image ----
    __syncthreads();                 // all waves done with K buffers
    float* Pb = (float*)smem;        // grp=1 partials: 256 lanes x 17 f32
    if (grp == 1) {
        float* dst = Pb + (size_t)(wq*64 + lane)*17;
        #pragma unroll
        for (int tt = 0; tt < 4; ++tt)
            #pragma unroll
            for (int r = 0; r < 4; ++r)
                dst[4*tt + r] = accOT[tt][r];
        dst[16] = lsum;
    }
    __syncthreads();
    float* Lt = (float*)(smem + 17920);  // 64 rows x 66 f32 = 16896 B
    if (grp == 0) {
        const float* sp = Pb + (size_t)(wq*64 + lane)*17;
        #pragma unroll
        for (int tt = 0; tt < 4; ++tt)
            #pragma unroll
            for (int r = 0; r < 4; ++r)
                accOT[tt][r] += sp[4*tt + r];
        float l = lsum + sp[16];
        l += __shfl_xor(l, 16);
        l += __shfl_xor(l, 32);
        float inv = 1.0f / l;
        const int row = 16*wq + cl;  // q row
        #pragma unroll
        for (int tt = 0; tt < 4; ++tt)
            #pragma unroll
            for (int r = 0; r < 4; ++r)
                Lt[row*66 + 16*tt + 4*qd + r] = accOT[tt][r] * inv;
    }
    __syncthreads();
    {
        const int r0 = tid >> 3;     // 0..63 (q row)
        const int qq = tid & 7;      // 8-col chunk
        float f[8];
        #pragma unroll
        for (int u = 0; u < 4; ++u)
            *(float2*)(f + 2*u) = *(const float2*)(&Lt[r0*66 + qq*8 + 2*u]);
        const int R = (qt & 1)*64 + r0;              // row within 128-row Y tile
        char* tile = Yimg + (size_t)((b*16 + (qt >> 1))*16 + h) * 32768;
        uint4 h4, l4;
        split_pack8(f, h4, l4);
        int phys = qq ^ (R & 7);
        *(uint4*)(tile + R*128 + phys*16)         = h4;
        *(uint4*)(tile + 16384 + R*128 + phys*16) = l4;
    }
}

// ---------------------------------------------------------------------------
extern "C" void kernel_launch(void* const* d_in, const int* in_sizes, int n_in,
                              void* d_out, int out_size, void* d_ws, size_t ws_size,
                              hipStream_t stream) {
    const float* x    = (const float*)d_in[0];
    const float* cosp = (const float*)d_in[1];
    const float* sinp = (const float*)d_in[2];
    // d_in[3] = mask: unused by the reference computation
    const float* Wqkv = (const float*)d_in[4];
    const float* Wout = (const float*)d_in[5];
    float* out = (float*)d_out;

    char* ws = (char*)d_ws;
    float*  Qf    = (float*)(ws);                      // [ 0,16M)
    ushort* Kimg  = (ushort*)(ws + ((size_t)16<<20));  // [16,20M)
    ushort* Vimg  = (ushort*)(ws + ((size_t)20<<20));  // [20,24M)
    char*   Bo    = ws + ((size_t)24<<20);             // [24,28M)
    char*   Ximg  = ws + ((size_t)28<<20);             // [28,44M)  (dead after qkv-gemm)
    char*   Bq    = ws + ((size_t)44<<20);             // [44,50M)
    char*   Yimg  = ws + ((size_t)28<<20);             // [28,44M)  (over dead Ximg)

    // 1) input + weight images
    conv_xy<<<512, 256, 0, stream>>>(x, Ximg);
    conv_w<<<dim3(16, 12), 256, 0, stream>>>(Wqkv, FQKV, Bq);
    conv_w<<<dim3(16, 8), 256, 0, stream>>>(Wout, DEMBED, Bo);
    // 2) qkv projection + fused RoPE + K/V image build
    gemm_qkv_mfma<<<dim3(12, 32), 256, 0, stream>>>(Ximg, Bq, cosp, sinp,
                                                    Qf, Kimg, Vimg);
    // 3) attention (1024 blocks x 512 thr; resource-limited occupancy)
    attn13<<<1024, 512, 0, stream>>>(Qf, (const char*)Kimg, (const char*)Vimg,
                                     Yimg);
    // 4) out = y @ Wout
    gemm_out_mfma<<<dim3(8, 64), 256, 0, stream>>>(Yimg, Bo, out);
}

// Round 8
// 230.086 us; speedup vs baseline: 1.6387x; 1.0622x over previous
//
#include <hip/hip_runtime.h>
#include <hip/hip_bf16.h>
#include <math.h>

// Problem constants (fixed shapes)
#define BATCH   2
#define TSEQ    2048
#define DEMBED  1024
#define NHEAD   16
#define DHEAD   64
#define NGROUP  4
#define ROPEN   32
#define FQKV    1536          // (16 + 2*4) * 64
#define MROWS   (BATCH*TSEQ)  // 4096

typedef __attribute__((ext_vector_type(8))) short short8;   // 8 bf16 = 4 VGPR
typedef __attribute__((ext_vector_type(4))) float floatx4;  // MFMA C/D

// ---------------------------------------------------------------------------
// split helpers: f = hi + lo, hi = truncate-to-bf16(f), lo = bf16(f - hi).
// ---------------------------------------------------------------------------
__device__ __forceinline__ void split_pack8(const float* f, uint4& h4, uint4& l4) {
    uint u[8], lu[8];
    #pragma unroll
    for (int j = 0; j < 8; ++j) {
        u[j] = __float_as_uint(f[j]);
        float lf = f[j] - __uint_as_float(u[j] & 0xffff0000u);
        lu[j] = __float_as_uint(lf);
    }
    h4.x = __builtin_amdgcn_perm(u[1], u[0], 0x07060302u);
    h4.y = __builtin_amdgcn_perm(u[3], u[2], 0x07060302u);
    h4.z = __builtin_amdgcn_perm(u[5], u[4], 0x07060302u);
    h4.w = __builtin_amdgcn_perm(u[7], u[6], 0x07060302u);
    l4.x = __builtin_amdgcn_perm(lu[1], lu[0], 0x07060302u);
    l4.y = __builtin_amdgcn_perm(lu[3], lu[2], 0x07060302u);
    l4.z = __builtin_amdgcn_perm(lu[5], lu[4], 0x07060302u);
    l4.w = __builtin_amdgcn_perm(lu[7], lu[6], 0x07060302u);
}

// round-to-nearest bf16 pack of 8 floats -> hi-only uint4 (unbiased)
__device__ __forceinline__ void rtn_pack8(const float* f, uint4& h4) {
    uint t[8];
    #pragma unroll
    for (int j = 0; j < 8; ++j)
        t[j] = __float_as_uint(f[j]) + 0x8000u;
    h4.x = __builtin_amdgcn_perm(t[1], t[0], 0x07060302u);
    h4.y = __builtin_amdgcn_perm(t[3], t[2], 0x07060302u);
    h4.z = __builtin_amdgcn_perm(t[5], t[4], 0x07060302u);
    h4.w = __builtin_amdgcn_perm(t[7], t[6], 0x07060302u);
}

// pack two floats -> one u32 of two RTN bf16 (lo = f0, hi = f1)
__device__ __forceinline__ uint pk_bf16x2(float f0, float f1) {
    uint u0 = __float_as_uint(f0) + 0x8000u;
    uint u1 = __float_as_uint(f1) + 0x8000u;
    return __builtin_amdgcn_perm(u1, u0, 0x07060302u);
}

// native 2^x (single VOP1; log2 scaling folded into operands upstream)
__device__ __forceinline__ float fast_exp2(float x) {
    float r;
    asm("v_exp_f32 %0, %1" : "=v"(r) : "v"(x));
    return r;
}

// async 16B/lane global->LDS copy; lds must be wave-uniform (HW adds lane*16)
__device__ __forceinline__ void lds_async16(void* lds, const void* gp) {
    __builtin_amdgcn_global_load_lds(
        (const __attribute__((address_space(1))) unsigned int*)gp,
        (__attribute__((address_space(3))) unsigned int*)lds,
        16, 0, 0);
}

// ===========================================================================
// MFMA-GEMM: pre-swizzled hi/lo bf16 images.
// Image layout (A and B^T): per (tile128, kblock64):
//   [hi: 128 rows x 128B][lo: 128 rows x 128B] = 32 KB, tile index = rt*16 + c.
//   Row r holds 64 bf16 k-values as 8 chunks of 16B; chunk j at phys j^(r&7).
// ===========================================================================

// ---- x converter: [4096][1024] f32 row-major -> A-image ----
__global__ __launch_bounds__(256) void conv_xy(const float* __restrict__ in,
                                               char* __restrict__ img) {
    const int tid = threadIdx.x;
    const int c   = blockIdx.x & 15;
    const int mt  = blockIdx.x >> 4;
    const int r    = tid >> 1;
    const int half = tid & 1;

    const float* src = in + (size_t)(mt*128 + r)*1024 + c*64 + half*32;
    float f[32];
    #pragma unroll
    for (int u = 0; u < 8; ++u)
        *(float4*)(f + 4*u) = *(const float4*)(src + 4*u);

    char* tile = img + ((size_t)(mt*16 + c)) * 32768;
    #pragma unroll
    for (int cc = 0; cc < 4; ++cc) {
        uint4 h4, l4;
        split_pack8(f + cc*8, h4, l4);
        int j    = half*4 + cc;
        int phys = j ^ (r & 7);
        *(uint4*)(tile + r*128 + phys*16)         = h4;
        *(uint4*)(tile + 16384 + r*128 + phys*16) = l4;
    }
}

// ---- weight converter (transpose): W [1024][N] f32 -> B^T image ----
__global__ __launch_bounds__(256) void conv_w(const float* __restrict__ W,
                                              int N,
                                              char* __restrict__ img) {
    __shared__ float Lf[64][132];
    const int tid = threadIdx.x;
    const int c   = blockIdx.x;
    const int nt  = blockIdx.y;

    {
        const int kk = tid >> 2;
        const int nc = (tid & 3) * 32;
        const float* src = W + (size_t)(c*64 + kk)*N + nt*128 + nc;
        #pragma unroll
        for (int u = 0; u < 8; ++u)
            *(float4*)(&Lf[kk][nc + 4*u]) = *(const float4*)(src + 4*u);
    }
    __syncthreads();

    char* tile = img + ((size_t)(nt*16 + c)) * 32768;
    #pragma unroll
    for (int rep = 0; rep < 4; ++rep) {
        int idx = rep*256 + tid;
        int n = idx & 127;
        int j = idx >> 7;
        float v[8];
        #pragma unroll
        for (int i = 0; i < 8; ++i) v[i] = Lf[j*8 + i][n];
        uint4 h4, l4;
        split_pack8(v, h4, l4);
        int phys = j ^ (n & 7);
        *(uint4*)(tile + n*128 + phys*16)         = h4;
        *(uint4*)(tile + 16384 + n*128 + phys*16) = l4;
    }
}

// ---- split-bf16 MFMA GEMM core: 128x128 tile, BK=64, 4 waves (2x2) ----
struct GemmAcc { floatx4 a[4][4]; };

__device__ __forceinline__ void gemm_mfma_core(const char* __restrict__ Aimg,
                                               const char* __restrict__ Bimg,
                                               char* smem, int mt, int nt,
                                               int tid, GemmAcc& G) {
    const int wv = tid >> 6;
    const int wm = wv & 1, wn = wv >> 1;
    const int lane = tid & 63;
    const int qd = lane >> 4, cl = lane & 15;
    const int wslot = (tid & 192) * 16;     // wave-uniform LDS byte offset

    #pragma unroll
    for (int tm = 0; tm < 4; ++tm)
        #pragma unroll
        for (int tn = 0; tn < 4; ++tn)
            G.a[tm][tn] = (floatx4){0.f, 0.f, 0.f, 0.f};

    for (int c = 0; c < 16; ++c) {
        __syncthreads();                    // prev-iter LDS reads complete
        {
            const uint4* gA = (const uint4*)(Aimg + ((size_t)(mt*16 + c)) * 32768) + tid;
            const uint4* gB = (const uint4*)(Bimg + ((size_t)(nt*16 + c)) * 32768) + tid;
            #pragma unroll
            for (int j = 0; j < 8; ++j) {
                lds_async16(smem + j*4096 + wslot,         gA + j*256);
                lds_async16(smem + 32768 + j*4096 + wslot, gB + j*256);
            }
        }
        __syncthreads();                    // vmcnt(0) drain publishes tile

        #pragma unroll
        for (int s = 0; s < 2; ++s) {
            const int phys = ((s*4 + qd) ^ (cl & 7)) * 16;
            short8 ah[4], al[4], bh[4], bl[4];
            #pragma unroll
            for (int tt = 0; tt < 4; ++tt) {
                const int rA = wm*64 + 16*tt + cl;
                ah[tt] = *(const short8*)(smem + rA*128 + phys);
                al[tt] = *(const short8*)(smem + 16384 + rA*128 + phys);
                const int rB = wn*64 + 16*tt + cl;
                bh[tt] = *(const short8*)(smem + 32768 + rB*128 + phys);
                bl[tt] = *(const short8*)(smem + 49152 + rB*128 + phys);
            }
            #pragma unroll
            for (int tm = 0; tm < 4; ++tm)
                #pragma unroll
                for (int tn = 0; tn < 4; ++tn) {
                    G.a[tm][tn] = __builtin_amdgcn_mfma_f32_16x16x32_bf16(ah[tm], bh[tn], G.a[tm][tn], 0, 0, 0);
                    G.a[tm][tn] = __builtin_amdgcn_mfma_f32_16x16x32_bf16(al[tm], bh[tn], G.a[tm][tn], 0, 0, 0);
                    G.a[tm][tn] = __builtin_amdgcn_mfma_f32_16x16x32_bf16(ah[tm], bl[tn], G.a[tm][tn], 0, 0, 0);
                }
        }
    }
}

// ---- qkv projection with fused RoPE + K/V image epilogue ----
// V image chunk contents are permuted to match attn's in-register P layout:
// chunk j (=4*hh+qd) of a 64-key tile holds keys {32hh+4qd..+3} then
// {32hh+16+4qd..+3} (was {8j..8j+7}).  attn-side addresses unchanged.
__global__ __launch_bounds__(256, 2) void gemm_qkv_mfma(const char* __restrict__ Aimg,
                                                        const char* __restrict__ Bimg,
                                                        const float* __restrict__ cosp,
                                                        const float* __restrict__ sinp,
                                                        float* __restrict__ Qf,
                                                        ushort* __restrict__ Kimg,
                                                        ushort* __restrict__ Vimg) {
    __shared__ __align__(16) char smem[68608];   // main loop uses [0,65536)
    const int tid = threadIdx.x;
    const int nt = blockIdx.x, mt = blockIdx.y;

    GemmAcc G;
    gemm_mfma_core(Aimg, Bimg, smem, mt, nt, tid, G);

    const int wv = tid >> 6;
    const int wm = wv & 1, wn = wv >> 1;
    const int lane = tid & 63;
    const int qd = lane >> 4, cl = lane & 15;

    const int slice = nt*2 + wn;          // 0..23
    const int g  = slice / 6;
    const int jj = slice % 6;
    const int b  = mt >> 4;

    // ---- RoPE in C-fragment space (Q and K): dims cl (tn=0) & 16+cl (tn=1)
    if (jj != 5) {
        #pragma unroll
        for (int tm = 0; tm < 4; ++tm)
            #pragma unroll
            for (int r = 0; r < 4; ++r) {
                int m = mt*128 + wm*64 + 16*tm + 4*qd + r;
                int t = m & 2047;
                float c1 = cosp[t*ROPEN + cl],      s1 = sinp[t*ROPEN + cl];
                float c2 = cosp[t*ROPEN + 16 + cl], s2 = sinp[t*ROPEN + 16 + cl];
                float x1 = G.a[tm][0][r], x2 = G.a[tm][1][r];
                G.a[tm][0][r] = x1*c1 - x2*s1;
                G.a[tm][1][r] = x2*c2 + x1*s2;
            }
    }

    if (jj < 4) {
        #pragma unroll
        for (int tm = 0; tm < 4; ++tm)
            #pragma unroll
            for (int tn = 0; tn < 4; ++tn)
                #pragma unroll
                for (int r = 0; r < 4; ++r) {
                    int m = mt*128 + wm*64 + 16*tm + 4*qd + r;
                    Qf[(size_t)m*1024 + (g*4 + jj)*64 + 16*tn + cl] = G.a[tm][tn][r];
                }
    } else {
        // K/V: wave-private LDS transpose -> swizzled image
        // K: exact hi/lo split (truncate).  V: RTN hi only (attn uses hi only).
        float* Lw = (float*)(smem + wv*17152);   // 64 x 67 f32
        __syncthreads();   // main-loop LDS reads complete (uniform: KV block)
        #pragma unroll
        for (int tm = 0; tm < 4; ++tm)
            #pragma unroll
            for (int tn = 0; tn < 4; ++tn)
                #pragma unroll
                for (int r = 0; r < 4; ++r)
                    Lw[(16*tm + 4*qd + r)*67 + 16*tn + cl] = G.a[tm][tn][r];
        __syncthreads();

        const int cloc = (mt & 15)*2 + wm;       // 64-key tile index within b
        ushort* img = ((jj == 4) ? Kimg : Vimg)
                      + (size_t)(b*4 + g)*262144 + (size_t)cloc*8192;
        if (jj == 4) {
            const int rr = lane;
            float f[8];
            #pragma unroll
            for (int ch = 0; ch < 8; ++ch) {
                *(float4*)f       = *(const float4*)(&Lw[rr*67 + ch*8]);
                *(float4*)(f + 4) = *(const float4*)(&Lw[rr*67 + ch*8 + 4]);
                uint4 h4, l4;
                split_pack8(f, h4, l4);
                int phys = ch ^ (rr & 7);
                *(uint4*)(img + rr*64 + phys*8)        = h4;
                *(uint4*)(img + 4096 + rr*64 + phys*8) = l4;
            }
        } else {
            // V: permuted-key chunk layout (see header comment)
            const int d = lane;
            float f[8];
            #pragma unroll
            for (int ch = 0; ch < 8; ++ch) {
                const int kb = 32*(ch >> 2) + 4*(ch & 3);
                #pragma unroll
                for (int i = 0; i < 4; ++i) f[i]     = Lw[(kb + i)*67 + d];
                #pragma unroll
                for (int i = 0; i < 4; ++i) f[4 + i] = Lw[(kb + 16 + i)*67 + d];
                uint4 h4;
                rtn_pack8(f, h4);
                int phys = ch ^ (d & 7);
                *(uint4*)(img + d*64 + phys*8) = h4;   // hi only
            }
        }
    }
}

// ---- output projection: out = yb @ Wout, 64M x 128N tiles ----
__global__ __launch_bounds__(256, 2) void gemm_out_mfma(const char* __restrict__ Aimg,
                                                        const char* __restrict__ Bimg,
                                                        float* __restrict__ C) {
    __shared__ __align__(16) char smem[49152];
    const int tid = threadIdx.x;
    const int nt = blockIdx.x, mt = blockIdx.y;   // mt: 64-row tile (0..63)

    const int wv = tid >> 6;
    const int wm = wv & 1, wn = wv >> 1;
    const int lane = tid & 63;
    const int qd = lane >> 4, cl = lane & 15;
    const int wslot = (tid & 192) * 16;

    floatx4 acc[2][4];
    #pragma unroll
    for (int tm = 0; tm < 2; ++tm)
        #pragma unroll
        for (int tn = 0; tn < 4; ++tn)
            acc[tm][tn] = (floatx4){0.f, 0.f, 0.f, 0.f};

    for (int c = 0; c < 16; ++c) {
        __syncthreads();
        {
            const char* sA = Aimg + ((size_t)((mt >> 1)*16 + c))*32768
                                  + (mt & 1)*8192 + (size_t)tid*16;
            const char* sB = Bimg + ((size_t)(nt*16 + c))*32768 + (size_t)tid*16;
            lds_async16(smem + wslot,          sA);
            lds_async16(smem + 4096  + wslot,  sA + 4096);
            lds_async16(smem + 8192  + wslot,  sA + 16384);
            lds_async16(smem + 12288 + wslot,  sA + 16384 + 4096);
            #pragma unroll
            for (int j = 0; j < 4; ++j) {
                lds_async16(smem + 16384 + j*4096 + wslot, sB + j*4096);
                lds_async16(smem + 32768 + j*4096 + wslot, sB + 16384 + j*4096);
            }
        }
        __syncthreads();

        #pragma unroll
        for (int s = 0; s < 2; ++s) {
            const int phys = ((s*4 + qd) ^ (cl & 7)) * 16;
            short8 ah[2], al[2], bh[4], bl[4];
            #pragma unroll
            for (int tt = 0; tt < 2; ++tt) {
                const int rA = wm*32 + 16*tt + cl;
                ah[tt] = *(const short8*)(smem + rA*128 + phys);
                al[tt] = *(const short8*)(smem + 8192 + rA*128 + phys);
            }
            #pragma unroll
            for (int tt = 0; tt < 4; ++tt) {
                const int rB = wn*64 + 16*tt + cl;
                bh[tt] = *(const short8*)(smem + 16384 + rB*128 + phys);
                bl[tt] = *(const short8*)(smem + 32768 + rB*128 + phys);
            }
            #pragma unroll
            for (int tm = 0; tm < 2; ++tm)
                #pragma unroll
                for (int tn = 0; tn < 4; ++tn) {
                    acc[tm][tn] = __builtin_amdgcn_mfma_f32_16x16x32_bf16(ah[tm], bh[tn], acc[tm][tn], 0, 0, 0);
                    acc[tm][tn] = __builtin_amdgcn_mfma_f32_16x16x32_bf16(al[tm], bh[tn], acc[tm][tn], 0, 0, 0);
                    acc[tm][tn] = __builtin_amdgcn_mfma_f32_16x16x32_bf16(ah[tm], bl[tn], acc[tm][tn], 0, 0, 0);
                }
        }
    }

    #pragma unroll
    for (int tm = 0; tm < 2; ++tm)
        #pragma unroll
        for (int tn = 0; tn < 4; ++tn)
            #pragma unroll
            for (int r = 0; r < 4; ++r) {
                int m = mt*64 + wm*32 + 16*tm + 4*qd + r;
                int n = nt*128 + wn*64 + 16*tn + cl;
                C[(size_t)m*1024 + n] = acc[tm][tn][r];
            }
}

// ---------------------------------------------------------------------------
// MFMA flash attention v14.  Diagnosis: v11/v13 both plateau ~87-94 us with
// MfmaUtil ~30% regardless of wave count -> the shared per-CU L1/TA port
// (~64 B/cy) is the bottleneck, not latency.  v13 pulled 6 KB/wave-round
// through the global port (4 KB direct V -- 4x redundant across the wq
// waves -- + 2 KB K staging) = ~96 cy/round vs the MFMA pipe's ~48 cy.
// v14 stages V through LDS as well (1 KB/wave-round async): global port
// drops to 3 KB/round, balancing TA with MFMA.  The V LDS copy is linear
// (image layout), so PV operands become ds_read_b128 at the SAME offsets;
// math is bit-identical.  The LDS pipe (256 B/cy) absorbs the extra reads.
// Structure otherwise = v13: 512-thr blocks, 8 waves (grp x wq), K dbuf,
// register-resident P (permuted V image), partials combined via LDS.
// LDS: K dbuf 32K | V dbuf 16K = 48K -> 3 blocks/CU (24 waves/CU >= the
// ~12 actually observed, so no practical residency loss).
// ---------------------------------------------------------------------------
__global__ __launch_bounds__(512, 4) void attn14(const float* __restrict__ Qf,
                                                 const char* __restrict__ Kimg,
                                                 const char* __restrict__ Vimg,
                                                 char* __restrict__ Yimg) {
    __shared__ __align__(16) char smem[49152];   // K dbuf 32K | V dbuf 16K

    const int tid  = threadIdx.x;
    const int wv8  = tid >> 6;           // 0..7
    const int grp  = wv8 >> 2;           // key half within 64-key tile
    const int wq   = wv8 & 3;            // q quarter (16 rows)
    const int lane = tid & 63;
    const int qd   = lane >> 4;
    const int cl   = lane & 15;

    const int bg    = blockIdx.x & 7;    // XCD-aligned
    const int inner = blockIdx.x >> 3;
    const int hj    = inner >> 5;        // head within group (0..3)
    const int qt    = inner & 31;        // 64-row q tile (0..31)
    const int b = bg >> 2, g = bg & 3;
    const int h = g*4 + hj;

    // ---- Q fragments (rows 16*wq..+15) -> registers, scaled log2(e)/8 ----
    short8 qh[2], ql[2];
    {
        const float* qp = Qf + (size_t)(b*2048 + qt*64 + wq*16 + cl)*1024
                             + h*64 + 8*qd;
        #pragma unroll
        for (int s = 0; s < 2; ++s) {
            float f[8];
            *(float4*)f       = *(const float4*)(qp + 32*s);
            *(float4*)(f + 4) = *(const float4*)(qp + 32*s + 4);
            #pragma unroll
            for (int i = 0; i < 8; ++i) f[i] *= 0.125f * 1.44269504088896f;
            uint4 h4, l4;
            split_pack8(f, h4, l4);
            qh[s] = __builtin_bit_cast(short8, h4);
            ql[s] = __builtin_bit_cast(short8, l4);
        }
    }

    floatx4 accOT[4] = {};               // O^T partial: [d-block], q = cl
    float lsum = 0.f;                    // softmax denom partial

    const char* Kg0 = Kimg + (size_t)bg*524288;
    const char* Vg0 = Vimg + (size_t)bg*524288;
    const int wslot = wv8 << 10;         // wave-uniform LDS byte offset (1K)

    // lane-constant V LDS offsets (chunk 4*grp+qd, phys ^(cl&7); 8K tile)
    int voff[4];
    #pragma unroll
    for (int tt = 0; tt < 4; ++tt)
        voff[tt] = (16*tt + cl)*128 + (((4*grp + qd) ^ (cl & 7))*16);

    // stage K 64-key tile 0 (hi 8K + lo 8K) + V tile 0 (8K), image-linear:
    // per thread: 2 K asyncs + 1 V async (16 B each)
    {
        const char* ksrc = Kg0 + (size_t)tid*16;
        lds_async16(smem + wslot,        ksrc);
        lds_async16(smem + 8192 + wslot, ksrc + 8192);
        lds_async16(smem + 32768 + wslot, Vg0 + (size_t)tid*16);
    }

    for (int c = 0; c < TSEQ/64; ++c) {
        __syncthreads();   // publishes K[c] + V[c]; all reads of c-1 complete
        const int buf = c & 1;

        if (c + 1 < TSEQ/64) {
            const char* ksrc = Kg0 + (size_t)(c+1)*16384 + (size_t)tid*16;
            const char* vsrc = Vg0 + (size_t)(c+1)*16384 + (size_t)tid*16;
            lds_async16(smem + (1-buf)*16384 + wslot,        ksrc);
            lds_async16(smem + (1-buf)*16384 + 8192 + wslot, ksrc + 8192);
            lds_async16(smem + 32768 + (1-buf)*8192 + wslot, vsrc);
        }
        const char* Kl = smem + buf*16384;
        const char* Vl = smem + 32768 + buf*8192;

        // ---- S^T = K.Q^T for this wave's 32-key half (3-pass split) ----
        floatx4 accST[2] = {};
        __builtin_amdgcn_s_setprio(1);
        #pragma unroll
        for (int s = 0; s < 2; ++s) {
            #pragma unroll
            for (int tt = 0; tt < 2; ++tt) {
                const int off = (32*grp + 16*tt + cl)*128
                              + (((4*s + qd) ^ (cl & 7))*16);
                short8 kh = *(const short8*)(Kl + off);
                short8 kl = *(const short8*)(Kl + 8192 + off);
                accST[tt] = __builtin_amdgcn_mfma_f32_16x16x32_bf16(kh, qh[s], accST[tt], 0, 0, 0);
                accST[tt] = __builtin_amdgcn_mfma_f32_16x16x32_bf16(kh, ql[s], accST[tt], 0, 0, 0);
                accST[tt] = __builtin_amdgcn_mfma_f32_16x16x32_bf16(kl, qh[s], accST[tt], 0, 0, 0);
            }
        }
        __builtin_amdgcn_s_setprio(0);

        // ---- softmax: exp2 (S in log2 units), pack in-register ----
        float p[8];
        #pragma unroll
        for (int tt = 0; tt < 2; ++tt)
            #pragma unroll
            for (int r = 0; r < 4; ++r)
                p[4*tt + r] = fast_exp2(accST[tt][r]);
        lsum += ((p[0] + p[1]) + (p[2] + p[3]))
              + ((p[4] + p[5]) + (p[6] + p[7]));
        uint4 paw;
        paw.x = pk_bf16x2(p[0], p[1]);
        paw.y = pk_bf16x2(p[2], p[3]);
        paw.z = pk_bf16x2(p[4], p[5]);
        paw.w = pk_bf16x2(p[6], p[7]);
        short8 pa = __builtin_bit_cast(short8, paw);

        // ---- O^T += V.P (V from LDS; chunks pre-permuted to P key order) --
        __builtin_amdgcn_s_setprio(1);
        #pragma unroll
        for (int tt = 0; tt < 4; ++tt) {
            short8 vh = *(const short8*)(Vl + voff[tt]);
            accOT[tt] = __builtin_amdgcn_mfma_f32_16x16x32_bf16(vh, pa, accOT[tt], 0, 0, 0);
        }
        __builtin_amdgcn_s_setprio(0);
    }

    // ---- combine the two key-half groups, normalize, write y A-image ----
    __syncthreads();                 // all waves done with K/V buffers
    float* Pb = (float*)smem;        // grp=1 partials: 256 lanes x 17 f32
    if (grp == 1) {
        float* dst = Pb + (size_t)(wq*64 + lane)*17;
        #pragma unroll
        for (int tt = 0; tt < 4; ++tt)
            #pragma unroll
            for (int r = 0; r < 4; ++r)
                dst[4*tt + r] = accOT[tt][r];
        dst[16] = lsum;
    }
    __syncthreads();
    float* Lt = (float*)(smem + 17920);  // 64 rows x 66 f32 = 16896 B
    if (grp == 0) {
        const float* sp = Pb + (size_t)(wq*64 + lane)*17;
        #pragma unroll
        for (int tt = 0; tt < 4; ++tt)
            #pragma unroll
            for (int r = 0; r < 4; ++r)
                accOT[tt][r] += sp[4*tt + r];
        float l = lsum + sp[16];
        l += __shfl_xor(l, 16);
        l += __shfl_xor(l, 32);
        float inv = 1.0f / l;
        const int row = 16*wq + cl;  // q row
        #pragma unroll
        for (int tt = 0; tt < 4; ++tt)
            #pragma unroll
            for (int r = 0; r < 4; ++r)
                Lt[row*66 + 16*tt + 4*qd + r] = accOT[tt][r] * inv;
    }
    __syncthreads();
    {
        const int r0 = tid >> 3;     // 0..63 (q row)
        const int qq = tid & 7;      // 8-col chunk
        float f[8];
        #pragma unroll
        for (int u = 0; u < 4; ++u)
            *(float2*)(f + 2*u) = *(const float2*)(&Lt[r0*66 + qq*8 + 2*u]);
        const int R = (qt & 1)*64 + r0;              // row within 128-row Y tile
        char* tile = Yimg + (size_t)((b*16 + (qt >> 1))*16 + h) * 32768;
        uint4 h4, l4;
        split_pack8(f, h4, l4);
        int phys = qq ^ (R & 7);
        *(uint4*)(tile + R*128 + phys*16)         = h4;
        *(uint4*)(tile + 16384 + R*128 + phys*16) = l4;
    }
}

// ---------------------------------------------------------------------------
extern "C" void kernel_launch(void* const* d_in, const int* in_sizes, int n_in,
                              void* d_out, int out_size, void* d_ws, size_t ws_size,
                              hipStream_t stream) {
    const float* x    = (const float*)d_in[0];
    const float* cosp = (const float*)d_in[1];
    const float* sinp = (const float*)d_in[2];
    // d_in[3] = mask: unused by the reference computation
    const float* Wqkv = (const float*)d_in[4];
    const float* Wout = (const float*)d_in[5];
    float* out = (float*)d_out;

    char* ws = (char*)d_ws;
    float*  Qf    = (float*)(ws);                      // [ 0,16M)
    ushort* Kimg  = (ushort*)(ws + ((size_t)16<<20));  // [16,20M)
    ushort* Vimg  = (ushort*)(ws + ((size_t)20<<20));  // [20,24M)
    char*   Bo    = ws + ((size_t)24<<20);             // [24,28M)
    char*   Ximg  = ws + ((size_t)28<<20);             // [28,44M)  (dead after qkv-gemm)
    char*   Bq    = ws + ((size_t)44<<20);             // [44,50M)
    char*   Yimg  = ws + ((size_t)28<<20);             // [28,44M)  (over dead Ximg)

    // 1) input + weight images
    conv_xy<<<512, 256, 0, stream>>>(x, Ximg);
    conv_w<<<dim3(16, 12), 256, 0, stream>>>(Wqkv, FQKV, Bq);
    conv_w<<<dim3(16, 8), 256, 0, stream>>>(Wout, DEMBED, Bo);
    // 2) qkv projection + fused RoPE + K/V image build
    gemm_qkv_mfma<<<dim3(12, 32), 256, 0, stream>>>(Ximg, Bq, cosp, sinp,
                                                    Qf, Kimg, Vimg);
    // 3) attention (1024 blocks x 512 thr; K and V staged via LDS)
    attn14<<<1024, 512, 0, stream>>>(Qf, (const char*)Kimg, (const char*)Vimg,
                                     Yimg);
    // 4) out = y @ Wout
    gemm_out_mfma<<<dim3(8, 64), 256, 0, stream>>>(Yimg, Bo, out);
}

// Round 10
// 224.247 us; speedup vs baseline: 1.6813x; 1.0260x over previous
//
#include <hip/hip_runtime.h>
#include <hip/hip_bf16.h>
#include <math.h>

// Problem constants (fixed shapes)
#define BATCH   2
#define TSEQ    2048
#define DEMBED  1024
#define NHEAD   16
#define DHEAD   64
#define NGROUP  4
#define ROPEN   32
#define FQKV    1536          // (16 + 2*4) * 64
#define MROWS   (BATCH*TSEQ)  // 4096

typedef __attribute__((ext_vector_type(8))) short short8;   // 8 bf16 = 4 VGPR
typedef __attribute__((ext_vector_type(4))) float floatx4;  // MFMA C/D

// ---------------------------------------------------------------------------
// split helpers: f = hi + lo, hi = truncate-to-bf16(f), lo = bf16(f - hi).
// ---------------------------------------------------------------------------
__device__ __forceinline__ void split_pack8(const float* f, uint4& h4, uint4& l4) {
    uint u[8], lu[8];
    #pragma unroll
    for (int j = 0; j < 8; ++j) {
        u[j] = __float_as_uint(f[j]);
        float lf = f[j] - __uint_as_float(u[j] & 0xffff0000u);
        lu[j] = __float_as_uint(lf);
    }
    h4.x = __builtin_amdgcn_perm(u[1], u[0], 0x07060302u);
    h4.y = __builtin_amdgcn_perm(u[3], u[2], 0x07060302u);
    h4.z = __builtin_amdgcn_perm(u[5], u[4], 0x07060302u);
    h4.w = __builtin_amdgcn_perm(u[7], u[6], 0x07060302u);
    l4.x = __builtin_amdgcn_perm(lu[1], lu[0], 0x07060302u);
    l4.y = __builtin_amdgcn_perm(lu[3], lu[2], 0x07060302u);
    l4.z = __builtin_amdgcn_perm(lu[5], lu[4], 0x07060302u);
    l4.w = __builtin_amdgcn_perm(lu[7], lu[6], 0x07060302u);
}

// round-to-nearest bf16 pack of 8 floats -> hi-only uint4 (unbiased)
__device__ __forceinline__ void rtn_pack8(const float* f, uint4& h4) {
    uint t[8];
    #pragma unroll
    for (int j = 0; j < 8; ++j)
        t[j] = __float_as_uint(f[j]) + 0x8000u;
    h4.x = __builtin_amdgcn_perm(t[1], t[0], 0x07060302u);
    h4.y = __builtin_amdgcn_perm(t[3], t[2], 0x07060302u);
    h4.z = __builtin_amdgcn_perm(t[5], t[4], 0x07060302u);
    h4.w = __builtin_amdgcn_perm(t[7], t[6], 0x07060302u);
}

// pack two floats -> one u32 of two RTN bf16 (lo = f0, hi = f1)
__device__ __forceinline__ uint pk_bf16x2(float f0, float f1) {
    uint u0 = __float_as_uint(f0) + 0x8000u;
    uint u1 = __float_as_uint(f1) + 0x8000u;
    return __builtin_amdgcn_perm(u1, u0, 0x07060302u);
}

// native 2^x (single VOP1; log2 scaling folded into operands upstream)
__device__ __forceinline__ float fast_exp2(float x) {
    float r;
    asm("v_exp_f32 %0, %1" : "=v"(r) : "v"(x));
    return r;
}

// async 16B/lane global->LDS copy; lds must be wave-uniform (HW adds lane*16)
// INVARIANT (session-verified): LDS destination must stay < 64 KiB.
__device__ __forceinline__ void lds_async16(void* lds, const void* gp) {
    __builtin_amdgcn_global_load_lds(
        (const __attribute__((address_space(1))) unsigned int*)gp,
        (__attribute__((address_space(3))) unsigned int*)lds,
        16, 0, 0);
}

// ===========================================================================
// MFMA-GEMM: pre-swizzled hi/lo bf16 images.
// Image layout (A and B^T): per (tile128, kblock64):
//   [hi: 128 rows x 128B][lo: 128 rows x 128B] = 32 KB, tile index = rt*16 + c.
//   Row r holds 64 bf16 k-values as 8 chunks of 16B; chunk j at phys j^(r&7).
// ===========================================================================

// ---- x converter: [4096][1024] f32 row-major -> A-image ----
__global__ __launch_bounds__(256) void conv_xy(const float* __restrict__ in,
                                               char* __restrict__ img) {
    const int tid = threadIdx.x;
    const int c   = blockIdx.x & 15;
    const int mt  = blockIdx.x >> 4;
    const int r    = tid >> 1;
    const int half = tid & 1;

    const float* src = in + (size_t)(mt*128 + r)*1024 + c*64 + half*32;
    float f[32];
    #pragma unroll
    for (int u = 0; u < 8; ++u)
        *(float4*)(f + 4*u) = *(const float4*)(src + 4*u);

    char* tile = img + ((size_t)(mt*16 + c)) * 32768;
    #pragma unroll
    for (int cc = 0; cc < 4; ++cc) {
        uint4 h4, l4;
        split_pack8(f + cc*8, h4, l4);
        int j    = half*4 + cc;
        int phys = j ^ (r & 7);
        *(uint4*)(tile + r*128 + phys*16)         = h4;
        *(uint4*)(tile + 16384 + r*128 + phys*16) = l4;
    }
}

// ---- weight converter (transpose): W [1024][N] f32 -> B^T image ----
__global__ __launch_bounds__(256) void conv_w(const float* __restrict__ W,
                                              int N,
                                              char* __restrict__ img) {
    __shared__ float Lf[64][132];
    const int tid = threadIdx.x;
    const int c   = blockIdx.x;
    const int nt  = blockIdx.y;

    {
        const int kk = tid >> 2;
        const int nc = (tid & 3) * 32;
        const float* src = W + (size_t)(c*64 + kk)*N + nt*128 + nc;
        #pragma unroll
        for (int u = 0; u < 8; ++u)
            *(float4*)(&Lf[kk][nc + 4*u]) = *(const float4*)(src + 4*u);
    }
    __syncthreads();

    char* tile = img + ((size_t)(nt*16 + c)) * 32768;
    #pragma unroll
    for (int rep = 0; rep < 4; ++rep) {
        int idx = rep*256 + tid;
        int n = idx & 127;
        int j = idx >> 7;
        float v[8];
        #pragma unroll
        for (int i = 0; i < 8; ++i) v[i] = Lf[j*8 + i][n];
        uint4 h4, l4;
        split_pack8(v, h4, l4);
        int phys = j ^ (n & 7);
        *(uint4*)(tile + n*128 + phys*16)         = h4;
        *(uint4*)(tile + 16384 + n*128 + phys*16) = l4;
    }
}

// ---- split-bf16 MFMA GEMM core: 128x128 tile, BK=64, 4 waves (2x2) ----
// (round-8 verified form; all async-LDS destinations < 64 KiB)
struct GemmAcc { floatx4 a[4][4]; };

__device__ __forceinline__ void gemm_mfma_core(const char* __restrict__ Aimg,
                                               const char* __restrict__ Bimg,
                                               char* smem, int mt, int nt,
                                               int tid, GemmAcc& G) {
    const int wv = tid >> 6;
    const int wm = wv & 1, wn = wv >> 1;
    const int lane = tid & 63;
    const int qd = lane >> 4, cl = lane & 15;
    const int wslot = (tid & 192) * 16;     // wave-uniform LDS byte offset

    #pragma unroll
    for (int tm = 0; tm < 4; ++tm)
        #pragma unroll
        for (int tn = 0; tn < 4; ++tn)
            G.a[tm][tn] = (floatx4){0.f, 0.f, 0.f, 0.f};

    for (int c = 0; c < 16; ++c) {
        __syncthreads();                    // prev-iter LDS reads complete
        {
            const uint4* gA = (const uint4*)(Aimg + ((size_t)(mt*16 + c)) * 32768) + tid;
            const uint4* gB = (const uint4*)(Bimg + ((size_t)(nt*16 + c)) * 32768) + tid;
            #pragma unroll
            for (int j = 0; j < 8; ++j) {
                lds_async16(smem + j*4096 + wslot,         gA + j*256);
                lds_async16(smem + 32768 + j*4096 + wslot, gB + j*256);
            }
        }
        __syncthreads();                    // vmcnt(0) drain publishes tile

        #pragma unroll
        for (int s = 0; s < 2; ++s) {
            const int phys = ((s*4 + qd) ^ (cl & 7)) * 16;
            short8 ah[4], al[4], bh[4], bl[4];
            #pragma unroll
            for (int tt = 0; tt < 4; ++tt) {
                const int rA = wm*64 + 16*tt + cl;
                ah[tt] = *(const short8*)(smem + rA*128 + phys);
                al[tt] = *(const short8*)(smem + 16384 + rA*128 + phys);
                const int rB = wn*64 + 16*tt + cl;
                bh[tt] = *(const short8*)(smem + 32768 + rB*128 + phys);
                bl[tt] = *(const short8*)(smem + 49152 + rB*128 + phys);
            }
            #pragma unroll
            for (int tm = 0; tm < 4; ++tm)
                #pragma unroll
                for (int tn = 0; tn < 4; ++tn) {
                    G.a[tm][tn] = __builtin_amdgcn_mfma_f32_16x16x32_bf16(ah[tm], bh[tn], G.a[tm][tn], 0, 0, 0);
                    G.a[tm][tn] = __builtin_amdgcn_mfma_f32_16x16x32_bf16(al[tm], bh[tn], G.a[tm][tn], 0, 0, 0);
                    G.a[tm][tn] = __builtin_amdgcn_mfma_f32_16x16x32_bf16(ah[tm], bl[tn], G.a[tm][tn], 0, 0, 0);
                }
        }
    }
}

// ---- qkv projection with fused RoPE + K/V image epilogue ----
// V image chunk contents are permuted to match attn's in-register P layout:
// chunk j (=4*hh+qd) of a 64-key tile holds keys {32hh+4qd..+3} then
// {32hh+16+4qd..+3} (was {8j..8j+7}).  attn-side addresses unchanged.
__global__ __launch_bounds__(256, 2) void gemm_qkv_mfma(const char* __restrict__ Aimg,
                                                        const char* __restrict__ Bimg,
                                                        const float* __restrict__ cosp,
                                                        const float* __restrict__ sinp,
                                                        float* __restrict__ Qf,
                                                        ushort* __restrict__ Kimg,
                                                        ushort* __restrict__ Vimg) {
    __shared__ __align__(16) char smem[68608];   // main loop uses [0,65536)
    const int tid = threadIdx.x;
    const int nt = blockIdx.x, mt = blockIdx.y;

    GemmAcc G;
    gemm_mfma_core(Aimg, Bimg, smem, mt, nt, tid, G);

    const int wv = tid >> 6;
    const int wm = wv & 1, wn = wv >> 1;
    const int lane = tid & 63;
    const int qd = lane >> 4, cl = lane & 15;

    const int slice = nt*2 + wn;          // 0..23
    const int g  = slice / 6;
    const int jj = slice % 6;
    const int b  = mt >> 4;

    // ---- RoPE in C-fragment space (Q and K): dims cl (tn=0) & 16+cl (tn=1)
    if (jj != 5) {
        #pragma unroll
        for (int tm = 0; tm < 4; ++tm)
            #pragma unroll
            for (int r = 0; r < 4; ++r) {
                int m = mt*128 + wm*64 + 16*tm + 4*qd + r;
                int t = m & 2047;
                float c1 = cosp[t*ROPEN + cl],      s1 = sinp[t*ROPEN + cl];
                float c2 = cosp[t*ROPEN + 16 + cl], s2 = sinp[t*ROPEN + 16 + cl];
                float x1 = G.a[tm][0][r], x2 = G.a[tm][1][r];
                G.a[tm][0][r] = x1*c1 - x2*s1;
                G.a[tm][1][r] = x2*c2 + x1*s2;
            }
    }

    if (jj < 4) {
        #pragma unroll
        for (int tm = 0; tm < 4; ++tm)
            #pragma unroll
            for (int tn = 0; tn < 4; ++tn)
                #pragma unroll
                for (int r = 0; r < 4; ++r) {
                    int m = mt*128 + wm*64 + 16*tm + 4*qd + r;
                    Qf[(size_t)m*1024 + (g*4 + jj)*64 + 16*tn + cl] = G.a[tm][tn][r];
                }
    } else {
        // K/V: wave-private LDS transpose -> swizzled image
        // K: exact hi/lo split (truncate).  V: RTN hi only (attn uses hi only).
        float* Lw = (float*)(smem + wv*17152);   // 64 x 67 f32
        __syncthreads();   // main-loop LDS reads complete (uniform: KV block)
        #pragma unroll
        for (int tm = 0; tm < 4; ++tm)
            #pragma unroll
            for (int tn = 0; tn < 4; ++tn)
                #pragma unroll
                for (int r = 0; r < 4; ++r)
                    Lw[(16*tm + 4*qd + r)*67 + 16*tn + cl] = G.a[tm][tn][r];
        __syncthreads();

        const int cloc = (mt & 15)*2 + wm;       // 64-key tile index within b
        ushort* img = ((jj == 4) ? Kimg : Vimg)
                      + (size_t)(b*4 + g)*262144 + (size_t)cloc*8192;
        if (jj == 4) {
            const int rr = lane;
            float f[8];
            #pragma unroll
            for (int ch = 0; ch < 8; ++ch) {
                *(float4*)f       = *(const float4*)(&Lw[rr*67 + ch*8]);
                *(float4*)(f + 4) = *(const float4*)(&Lw[rr*67 + ch*8 + 4]);
                uint4 h4, l4;
                split_pack8(f, h4, l4);
                int phys = ch ^ (rr & 7);
                *(uint4*)(img + rr*64 + phys*8)        = h4;
                *(uint4*)(img + 4096 + rr*64 + phys*8) = l4;
            }
        } else {
            // V: permuted-key chunk layout (see header comment)
            const int d = lane;
            float f[8];
            #pragma unroll
            for (int ch = 0; ch < 8; ++ch) {
                const int kb = 32*(ch >> 2) + 4*(ch & 3);
                #pragma unroll
                for (int i = 0; i < 4; ++i) f[i]     = Lw[(kb + i)*67 + d];
                #pragma unroll
                for (int i = 0; i < 4; ++i) f[4 + i] = Lw[(kb + 16 + i)*67 + d];
                uint4 h4;
                rtn_pack8(f, h4);
                int phys = ch ^ (d & 7);
                *(uint4*)(img + d*64 + phys*8) = h4;   // hi only
            }
        }
    }
}

// ---- output projection: out = yb @ Wout, 64M x 128N tiles (round-8 form) --
__global__ __launch_bounds__(256, 2) void gemm_out_mfma(const char* __restrict__ Aimg,
                                                        const char* __restrict__ Bimg,
                                                        float* __restrict__ C) {
    __shared__ __align__(16) char smem[49152];
    const int tid = threadIdx.x;
    const int nt = blockIdx.x, mt = blockIdx.y;   // mt: 64-row tile (0..63)

    const int wv = tid >> 6;
    const int wm = wv & 1, wn = wv >> 1;
    const int lane = tid & 63;
    const int qd = lane >> 4, cl = lane & 15;
    const int wslot = (tid & 192) * 16;

    floatx4 acc[2][4];
    #pragma unroll
    for (int tm = 0; tm < 2; ++tm)
        #pragma unroll
        for (int tn = 0; tn < 4; ++tn)
            acc[tm][tn] = (floatx4){0.f, 0.f, 0.f, 0.f};

    for (int c = 0; c < 16; ++c) {
        __syncthreads();
        {
            const char* sA = Aimg + ((size_t)((mt >> 1)*16 + c))*32768
                                  + (mt & 1)*8192 + (size_t)tid*16;
            const char* sB = Bimg + ((size_t)(nt*16 + c))*32768 + (size_t)tid*16;
            lds_async16(smem + wslot,          sA);
            lds_async16(smem + 4096  + wslot,  sA + 4096);
            lds_async16(smem + 8192  + wslot,  sA + 16384);
            lds_async16(smem + 12288 + wslot,  sA + 16384 + 4096);
            #pragma unroll
            for (int j = 0; j < 4; ++j) {
                lds_async16(smem + 16384 + j*4096 + wslot, sB + j*4096);
                lds_async16(smem + 32768 + j*4096 + wslot, sB + 16384 + j*4096);
            }
        }
        __syncthreads();

        #pragma unroll
        for (int s = 0; s < 2; ++s) {
            const int phys = ((s*4 + qd) ^ (cl & 7)) * 16;
            short8 ah[2], al[2], bh[4], bl[4];
            #pragma unroll
            for (int tt = 0; tt < 2; ++tt) {
                const int rA = wm*32 + 16*tt + cl;
                ah[tt] = *(const short8*)(smem + rA*128 + phys);
                al[tt] = *(const short8*)(smem + 8192 + rA*128 + phys);
            }
            #pragma unroll
            for (int tt = 0; tt < 4; ++tt) {
                const int rB = wn*64 + 16*tt + cl;
                bh[tt] = *(const short8*)(smem + 16384 + rB*128 + phys);
                bl[tt] = *(const short8*)(smem + 32768 + rB*128 + phys);
            }
            #pragma unroll
            for (int tm = 0; tm < 2; ++tm)
                #pragma unroll
                for (int tn = 0; tn < 4; ++tn) {
                    acc[tm][tn] = __builtin_amdgcn_mfma_f32_16x16x32_bf16(ah[tm], bh[tn], acc[tm][tn], 0, 0, 0);
                    acc[tm][tn] = __builtin_amdgcn_mfma_f32_16x16x32_bf16(al[tm], bh[tn], acc[tm][tn], 0, 0, 0);
                    acc[tm][tn] = __builtin_amdgcn_mfma_f32_16x16x32_bf16(ah[tm], bl[tn], acc[tm][tn], 0, 0, 0);
                }
        }
    }

    #pragma unroll
    for (int tm = 0; tm < 2; ++tm)
        #pragma unroll
        for (int tn = 0; tn < 4; ++tn)
            #pragma unroll
            for (int r = 0; r < 4; ++r) {
                int m = mt*64 + wm*32 + 16*tm + 4*qd + r;
                int n = nt*128 + wn*64 + 16*tn + cl;
                C[(size_t)m*1024 + n] = acc[tm][tn][r];
            }
}

// ---------------------------------------------------------------------------
// MFMA flash attention v15.  attn14 was TA/MFMA co-bound; its 1024 blocks
// each staged the full 24 KB per 64-key tile.  v15 doubles q-rows per block
// (128 rows; 512 blocks = 2 blocks/CU = 16 waves/CU ~= attn14's measured
// effective occupancy) so every staged K/V tile feeds 2x the MFMA work:
// K ds_reads are shared across the new rb dimension (8 reads -> 24 S-MFMA),
// V reads feed 8 PV-MFMA.  TA and LDS-read demand per unit work halve.
// Main-loop sync structure IDENTICAL to attn14 (verified); all async-LDS
// destinations < 48 KiB.  Per-q-row numerics bit-identical.
// Epilogue: 4 uniform barriers (Pb partials | combine | Lt | y-image write).
// LDS: K dbuf 32K | V dbuf 16K = 48K.  VGPR ~100-110 (cap 128, no spill).
// ---------------------------------------------------------------------------
__global__ __launch_bounds__(512, 4) void attn15(const float* __restrict__ Qf,
                                                 const char* __restrict__ Kimg,
                                                 const char* __restrict__ Vimg,
                                                 char* __restrict__ Yimg) {
    __shared__ __align__(16) char smem[49152];   // K dbuf 32K | V dbuf 16K

    const int tid  = threadIdx.x;
    const int wv8  = tid >> 6;           // 0..7
    const int grp  = wv8 >> 2;           // key half within 64-key tile
    const int wq   = wv8 & 3;            // q quarter (32 rows)
    const int lane = tid & 63;
    const int qd   = lane >> 4;
    const int cl   = lane & 15;

    const int bg    = blockIdx.x & 7;    // XCD-aligned
    const int inner = blockIdx.x >> 3;   // 0..63
    const int hj    = inner >> 4;        // head within group (0..3)
    const int qt    = inner & 15;        // 128-row q tile (0..15)
    const int b = bg >> 2, g = bg & 3;
    const int h = g*4 + hj;

    // ---- Q fragments (rows wq*32 + rb*16 + cl) -> regs, scaled log2(e)/8 --
    short8 qh[2][2], ql[2][2];
    #pragma unroll
    for (int rb = 0; rb < 2; ++rb) {
        const float* qp = Qf + (size_t)(b*2048 + qt*128 + wq*32 + rb*16 + cl)*1024
                             + h*64 + 8*qd;
        #pragma unroll
        for (int s = 0; s < 2; ++s) {
            float f[8];
            *(float4*)f       = *(const float4*)(qp + 32*s);
            *(float4*)(f + 4) = *(const float4*)(qp + 32*s + 4);
            #pragma unroll
            for (int i = 0; i < 8; ++i) f[i] *= 0.125f * 1.44269504088896f;
            uint4 h4, l4;
            split_pack8(f, h4, l4);
            qh[rb][s] = __builtin_bit_cast(short8, h4);
            ql[rb][s] = __builtin_bit_cast(short8, l4);
        }
    }

    floatx4 accOT[2][4] = {};            // O^T partial: [rb][d-block], q = cl
    float lsum[2] = {};                  // softmax denom partials

    const char* Kg0 = Kimg + (size_t)bg*524288;
    const char* Vg0 = Vimg + (size_t)bg*524288;
    const int wslot = wv8 << 10;         // wave-uniform LDS byte offset (1K)

    // lane-constant V LDS offsets (chunk 4*grp+qd, phys ^(cl&7); 8K tile)
    int voff[4];
    #pragma unroll
    for (int tt = 0; tt < 4; ++tt)
        voff[tt] = (16*tt + cl)*128 + (((4*grp + qd) ^ (cl & 7))*16);

    // stage K 64-key tile 0 (hi 8K + lo 8K) + V tile 0 (8K), image-linear
    {
        const char* ksrc = Kg0 + (size_t)tid*16;
        lds_async16(smem + wslot,        ksrc);
        lds_async16(smem + 8192 + wslot, ksrc + 8192);
        lds_async16(smem + 32768 + wslot, Vg0 + (size_t)tid*16);
    }

    for (int c = 0; c < TSEQ/64; ++c) {
        __syncthreads();   // publishes K[c] + V[c]; all reads of c-1 complete
        const int buf = c & 1;

        if (c + 1 < TSEQ/64) {
            const char* ksrc = Kg0 + (size_t)(c+1)*16384 + (size_t)tid*16;
            const char* vsrc = Vg0 + (size_t)(c+1)*16384 + (size_t)tid*16;
            lds_async16(smem + (1-buf)*16384 + wslot,        ksrc);
            lds_async16(smem + (1-buf)*16384 + 8192 + wslot, ksrc + 8192);
            lds_async16(smem + 32768 + (1-buf)*8192 + wslot, vsrc);
        }
        const char* Kl = smem + buf*16384;
        const char* Vl = smem + 32768 + buf*8192;

        // ---- S^T = K.Q^T for this wave's 32-key half, BOTH row-blocks ----
        // K fragments read ONCE, used by both rb (the whole point of v15)
        floatx4 accST[2][2] = {};
        __builtin_amdgcn_s_setprio(1);
        #pragma unroll
        for (int s = 0; s < 2; ++s) {
            #pragma unroll
            for (int tt = 0; tt < 2; ++tt) {
                const int off = (32*grp + 16*tt + cl)*128
                              + (((4*s + qd) ^ (cl & 7))*16);
                short8 kh = *(const short8*)(Kl + off);
                short8 kl = *(const short8*)(Kl + 8192 + off);
                #pragma unroll
                for (int rb = 0; rb < 2; ++rb) {
                    accST[rb][tt] = __builtin_amdgcn_mfma_f32_16x16x32_bf16(kh, qh[rb][s], accST[rb][tt], 0, 0, 0);
                    accST[rb][tt] = __builtin_amdgcn_mfma_f32_16x16x32_bf16(kh, ql[rb][s], accST[rb][tt], 0, 0, 0);
                    accST[rb][tt] = __builtin_amdgcn_mfma_f32_16x16x32_bf16(kl, qh[rb][s], accST[rb][tt], 0, 0, 0);
                }
            }
        }
        __builtin_amdgcn_s_setprio(0);

        // ---- softmax: exp2 (S in log2 units), pack in-register ----
        short8 pa[2];
        #pragma unroll
        for (int rb = 0; rb < 2; ++rb) {
            float p[8];
            #pragma unroll
            for (int tt = 0; tt < 2; ++tt)
                #pragma unroll
                for (int r = 0; r < 4; ++r)
                    p[4*tt + r] = fast_exp2(accST[rb][tt][r]);
            lsum[rb] += ((p[0] + p[1]) + (p[2] + p[3]))
                      + ((p[4] + p[5]) + (p[6] + p[7]));
            uint4 paw;
            paw.x = pk_bf16x2(p[0], p[1]);
            paw.y = pk_bf16x2(p[2], p[3]);
            paw.z = pk_bf16x2(p[4], p[5]);
            paw.w = pk_bf16x2(p[6], p[7]);
            pa[rb] = __builtin_bit_cast(short8, paw);
        }

        // ---- O^T += V.P (V from LDS, read once per tt, feeds both rb) ----
        __builtin_amdgcn_s_setprio(1);
        #pragma unroll
        for (int tt = 0; tt < 4; ++tt) {
            short8 vh = *(const short8*)(Vl + voff[tt]);
            #pragma unroll
            for (int rb = 0; rb < 2; ++rb)
                accOT[rb][tt] = __builtin_amdgcn_mfma_f32_16x16x32_bf16(vh, pa[rb], accOT[rb][tt], 0, 0, 0);
        }
        __builtin_amdgcn_s_setprio(0);
    }

    // ---- combine key-half groups, normalize, write y A-image ----
    __syncthreads();                 // all waves done with K/V buffers
    float* Pb = (float*)smem;        // grp=1 partials: 512 entries x 17 f32
    if (grp == 1) {
        #pragma unroll
        for (int rb = 0; rb < 2; ++rb) {
            float* dst = Pb + (size_t)(((wq*2 + rb)*64) + lane)*17;
            #pragma unroll
            for (int tt = 0; tt < 4; ++tt)
                #pragma unroll
                for (int r = 0; r < 4; ++r)
                    dst[4*tt + r] = accOT[rb][tt][r];
            dst[16] = lsum[rb];
        }
    }
    __syncthreads();
    float inv[2] = {1.f, 1.f};
    if (grp == 0) {
        #pragma unroll
        for (int rb = 0; rb < 2; ++rb) {
            const float* sp = Pb + (size_t)(((wq*2 + rb)*64) + lane)*17;
            #pragma unroll
            for (int tt = 0; tt < 4; ++tt)
                #pragma unroll
                for (int r = 0; r < 4; ++r)
                    accOT[rb][tt][r] += sp[4*tt + r];
            float l = lsum[rb] + sp[16];
            l += __shfl_xor(l, 16);
            l += __shfl_xor(l, 32);
            inv[rb] = 1.0f / l;
        }
    }
    __syncthreads();                 // Pb reads done -> region reusable as Lt
    float* Lt = (float*)smem;        // 128 rows x 66 f32 = 33792 B
    if (grp == 0) {
        #pragma unroll
        for (int rb = 0; rb < 2; ++rb) {
            const int row = wq*32 + rb*16 + cl;  // q row in 128-tile
            #pragma unroll
            for (int tt = 0; tt < 4; ++tt)
                #pragma unroll
                for (int r = 0; r < 4; ++r)
                    Lt[row*66 + 16*tt + 4*qd + r] = accOT[rb][tt][r] * inv[rb];
        }
    }
    __syncthreads();
    {
        // 512 threads x 2 chunks = 1024 chunk-writes (128 rows x 8 chunks)
        char* tile = Yimg + (size_t)((b*16 + qt)*16 + h) * 32768;
        #pragma unroll
        for (int cc = 0; cc < 2; ++cc) {
            const int idx = tid*2 + cc;
            const int r0 = idx >> 3;     // 0..127 (q row)
            const int j  = idx & 7;      // 8-col chunk
            float f[8];
            #pragma unroll
            for (int u = 0; u < 4; ++u)
                *(float2*)(f + 2*u) = *(const float2*)(&Lt[r0*66 + j*8 + 2*u]);
            uint4 h4, l4;
            split_pack8(f, h4, l4);
            int phys = j ^ (r0 & 7);
            *(uint4*)(tile + r0*128 + phys*16)         = h4;
            *(uint4*)(tile + 16384 + r0*128 + phys*16) = l4;
        }
    }
}

// ---------------------------------------------------------------------------
extern "C" void kernel_launch(void* const* d_in, const int* in_sizes, int n_in,
                              void* d_out, int out_size, void* d_ws, size_t ws_size,
                              hipStream_t stream) {
    const float* x    = (const float*)d_in[0];
    const float* cosp = (const float*)d_in[1];
    const float* sinp = (const float*)d_in[2];
    // d_in[3] = mask: unused by the reference computation
    const float* Wqkv = (const float*)d_in[4];
    const float* Wout = (const float*)d_in[5];
    float* out = (float*)d_out;

    char* ws = (char*)d_ws;
    float*  Qf    = (float*)(ws);                      // [ 0,16M)
    ushort* Kimg  = (ushort*)(ws + ((size_t)16<<20));  // [16,20M)
    ushort* Vimg  = (ushort*)(ws + ((size_t)20<<20));  // [20,24M)
    char*   Bo    = ws + ((size_t)24<<20);             // [24,28M)
    char*   Ximg  = ws + ((size_t)28<<20);             // [28,44M)  (dead after qkv-gemm)
    char*   Bq    = ws + ((size_t)44<<20);             // [44,50M)
    char*   Yimg  = ws + ((size_t)28<<20);             // [28,44M)  (over dead Ximg)

    // 1) input + weight images
    conv_xy<<<512, 256, 0, stream>>>(x, Ximg);
    conv_w<<<dim3(16, 12), 256, 0, stream>>>(Wqkv, FQKV, Bq);
    conv_w<<<dim3(16, 8), 256, 0, stream>>>(Wout, DEMBED, Bo);
    // 2) qkv projection + fused RoPE + K/V image build (round-8 form)
    gemm_qkv_mfma<<<dim3(12, 32), 256, 0, stream>>>(Ximg, Bq, cosp, sinp,
                                                    Qf, Kimg, Vimg);
    // 3) attention: 512 blocks x 512 thr, 128 q-rows/block
    attn15<<<512, 512, 0, stream>>>(Qf, (const char*)Kimg, (const char*)Vimg,
                                    Yimg);
    // 4) out = y @ Wout (round-8 form)
    gemm_out_mfma<<<dim3(8, 64), 256, 0, stream>>>(Yimg, Bo, out);
}